// Round 1
// baseline (14377.841 us; speedup 1.0000x reference)
//
#include <hip/hip_runtime.h>
#include <hip/hip_bf16.h>
#include <math.h>

// Model dims (compile-time constants)
#define V_SZ 50257
#define E_SZ 512
#define H_N 8
#define L_N 8
#define HID_SZ 1365
#define T_SZ 1024
#define B_SZ 2
#define HD_SZ 64
#define ROWS (B_SZ * T_SZ)   // 2048

// ---------------------------------------------------------------------------
// Embedding: x[b,t,:] = W_emb[idx[b,t],:] + pos_emb[t,:]
// ---------------------------------------------------------------------------
__global__ __launch_bounds__(128) void embed_kernel(
    const int* __restrict__ idx, const float* __restrict__ W,
    const float* __restrict__ P, float* __restrict__ x) {
  const int bt = blockIdx.x;            // 0..2047
  const int t = bt & (T_SZ - 1);
  const int id = idx[bt];
  const int e = threadIdx.x * 4;        // 128 threads * float4 = 512
  float4 w = *(const float4*)(W + (size_t)id * E_SZ + e);
  float4 p = *(const float4*)(P + (size_t)t * E_SZ + e);
  float4 r;
  r.x = w.x + p.x; r.y = w.y + p.y; r.z = w.z + p.z; r.w = w.w + p.w;
  *(float4*)(x + (size_t)bt * E_SZ + e) = r;
}

// ---------------------------------------------------------------------------
// LayerNorm over E=512: one block (256 thr) per row, 2 floats/thread
// ---------------------------------------------------------------------------
__global__ __launch_bounds__(256) void ln_kernel(
    const float* __restrict__ in, float* __restrict__ out,
    const float* __restrict__ sc, const float* __restrict__ bi) {
  const int row = blockIdx.x;
  const int tid = threadIdx.x;
  const float2 v = *(const float2*)(in + (size_t)row * E_SZ + tid * 2);
  float s = v.x + v.y;
#pragma unroll
  for (int o = 32; o; o >>= 1) s += __shfl_xor(s, o);
  __shared__ float w1[4], w2[4];
  if ((tid & 63) == 0) w1[tid >> 6] = s;
  __syncthreads();
  const float mean = (w1[0] + w1[1] + w1[2] + w1[3]) * (1.f / 512.f);
  const float d0 = v.x - mean, d1 = v.y - mean;
  float q = d0 * d0 + d1 * d1;
#pragma unroll
  for (int o = 32; o; o >>= 1) q += __shfl_xor(q, o);
  if ((tid & 63) == 0) w2[tid >> 6] = q;
  __syncthreads();
  const float var = (w2[0] + w2[1] + w2[2] + w2[3]) * (1.f / 512.f);
  const float inv = rsqrtf(var + 1e-5f);
  const float2 sv = *(const float2*)(sc + tid * 2);
  const float2 bv = *(const float2*)(bi + tid * 2);
  float2 ov;
  ov.x = d0 * inv * sv.x + bv.x;
  ov.y = d1 * inv * sv.y + bv.y;
  *(float2*)(out + (size_t)row * E_SZ + tid * 2) = ov;
}

// ---------------------------------------------------------------------------
// Tiled f32 GEMM. C[M,N] = A[M,K] @ B  (+ R residual).
// NT=false: B is [K,N] row-major.  NT=true: B is [N,K] row-major (B^T used).
// 128x128 tile, BK=16, 256 threads, 8x8 microtile. M must be mult of 128.
// ---------------------------------------------------------------------------
template <bool NT, bool RES>
__global__ __launch_bounds__(256) void gemm_kernel(
    const float* __restrict__ A, const float* __restrict__ B,
    float* __restrict__ C, const float* __restrict__ R,
    int M, int N, int K) {
  __shared__ __align__(16) float As[16][132];
  __shared__ __align__(16) float Bs[16][132];
  const int tid = threadIdx.x;
  const int m0 = blockIdx.y * 128, n0 = blockIdx.x * 128;
  const int tx = tid & 15, ty = tid >> 4;
  float acc[8][8] = {};

  for (int k0 = 0; k0 < K; k0 += 16) {
    {  // A tile -> As[k][m]
      const int c = tid & 15, r = tid >> 4;
#pragma unroll
      for (int i = 0; i < 8; ++i) {
        const int m = r + 16 * i;
        float v = 0.f;
        if (k0 + c < K) v = A[(size_t)(m0 + m) * K + k0 + c];
        As[c][m] = v;
      }
    }
    if (NT) {  // B tile from [N,K]
      const int c = tid & 15, r = tid >> 4;
#pragma unroll
      for (int i = 0; i < 8; ++i) {
        const int n = r + 16 * i;
        float v = 0.f;
        if ((n0 + n) < N && (k0 + c) < K) v = B[(size_t)(n0 + n) * K + k0 + c];
        Bs[c][n] = v;
      }
    } else {  // B tile from [K,N]
      const int n = tid & 127, r = tid >> 7;
#pragma unroll
      for (int i = 0; i < 8; ++i) {
        const int k = r + 2 * i;
        float v = 0.f;
        if ((n0 + n) < N && (k0 + k) < K) v = B[(size_t)(k0 + k) * N + n0 + n];
        Bs[k][n] = v;
      }
    }
    __syncthreads();
#pragma unroll
    for (int k = 0; k < 16; ++k) {
      float a[8], b[8];
      *(float4*)&a[0] = *(const float4*)&As[k][ty * 8];
      *(float4*)&a[4] = *(const float4*)&As[k][ty * 8 + 4];
      *(float4*)&b[0] = *(const float4*)&Bs[k][tx * 8];
      *(float4*)&b[4] = *(const float4*)&Bs[k][tx * 8 + 4];
#pragma unroll
      for (int ii = 0; ii < 8; ++ii)
#pragma unroll
        for (int jj = 0; jj < 8; ++jj)
          acc[ii][jj] = fmaf(a[ii], b[jj], acc[ii][jj]);
    }
    __syncthreads();
  }

  const bool full = (n0 + 128) <= N;
#pragma unroll
  for (int ii = 0; ii < 8; ++ii) {
    const int m = m0 + ty * 8 + ii;
    float* crow = C + (size_t)m * N;
    const float* rrow = RES ? (R + (size_t)m * N) : nullptr;
    const int nb = n0 + tx * 8;
    if (full) {
      float4 v0, v1;
      v0.x = acc[ii][0]; v0.y = acc[ii][1]; v0.z = acc[ii][2]; v0.w = acc[ii][3];
      v1.x = acc[ii][4]; v1.y = acc[ii][5]; v1.z = acc[ii][6]; v1.w = acc[ii][7];
      if (RES) {
        float4 r0 = *(const float4*)(rrow + nb);
        float4 r1 = *(const float4*)(rrow + nb + 4);
        v0.x += r0.x; v0.y += r0.y; v0.z += r0.z; v0.w += r0.w;
        v1.x += r1.x; v1.y += r1.y; v1.z += r1.z; v1.w += r1.w;
      }
      *(float4*)(crow + nb) = v0;
      *(float4*)(crow + nb + 4) = v1;
    } else {
#pragma unroll
      for (int jj = 0; jj < 8; ++jj) {
        const int n = nb + jj;
        if (n < N) {
          float v = acc[ii][jj];
          if (RES) v += rrow[n];
          crow[n] = v;
        }
      }
    }
  }
}

// ---------------------------------------------------------------------------
// Attention: one wave (64 thr) per (b, h, query row i).
// qkv rows are [B*T, 3E]; q at col h*64, k at 512+h*64, v at 1024+h*64.
// scores = q.k * 0.125 + slope_h*(i-j) for j<=i; softmax; out = P @ V.
// ---------------------------------------------------------------------------
__global__ __launch_bounds__(64) void attn_kernel(
    const float* __restrict__ qkv, float* __restrict__ o) {
  const int bid = blockIdx.x;
  const int i = bid & (T_SZ - 1);
  const int h = (bid >> 10) & (H_N - 1);
  const int b = bid >> 13;
  const int lane = threadIdx.x;

  __shared__ __align__(16) float qs[64];
  __shared__ __align__(16) float sc[T_SZ];

  const size_t rowQ = ((size_t)(b * T_SZ + i)) * (3 * E_SZ) + h * HD_SZ;
  qs[lane] = qkv[rowQ + lane];
  __syncthreads();

  const float slope = exp2f(-(float)(h + 1));  // 1/2^(8*(h+1)/8)
  float mx = -1e30f;
  for (int j = lane; j <= i; j += 64) {
    const float* kr = qkv + ((size_t)(b * T_SZ + j)) * (3 * E_SZ) + E_SZ + h * HD_SZ;
    float dot = 0.f;
#pragma unroll
    for (int c = 0; c < 16; ++c) {
      float4 k4 = *(const float4*)(kr + c * 4);
      float4 q4 = *(const float4*)(qs + c * 4);
      dot += q4.x * k4.x + q4.y * k4.y + q4.z * k4.z + q4.w * k4.w;
    }
    float s = dot * 0.125f + slope * (float)(i - j);
    sc[j] = s;
    mx = fmaxf(mx, s);
  }
#pragma unroll
  for (int off = 32; off; off >>= 1) mx = fmaxf(mx, __shfl_xor(mx, off));
  float sum = 0.f;
  for (int j = lane; j <= i; j += 64) {
    float e = expf(sc[j] - mx);
    sc[j] = e;
    sum += e;
  }
#pragma unroll
  for (int off = 32; off; off >>= 1) sum += __shfl_xor(sum, off);
  __syncthreads();
  const float inv = 1.f / sum;

  float acc = 0.f;
  const float* vbase = qkv + (size_t)(b * T_SZ) * (3 * E_SZ) + 2 * E_SZ + h * HD_SZ + lane;
  for (int j = 0; j <= i; ++j) {
    acc += sc[j] * vbase[(size_t)j * (3 * E_SZ)];
  }
  o[((size_t)(b * T_SZ + i)) * E_SZ + h * HD_SZ + lane] = acc * inv;
}

// ---------------------------------------------------------------------------
// SwiGLU elementwise: g = g * sigmoid(g) * u
// ---------------------------------------------------------------------------
__global__ __launch_bounds__(256) void swiglu_kernel(
    float* __restrict__ g, const float* __restrict__ u, int n) {
  const int i = blockIdx.x * 256 + threadIdx.x;
  if (i < n) {
    const float gv = g[i];
    const float s = 1.f / (1.f + expf(-gv));
    g[i] = gv * s * u[i];
  }
}

// ---------------------------------------------------------------------------
extern "C" void kernel_launch(void* const* d_in, const int* in_sizes, int n_in,
                              void* d_out, int out_size, void* d_ws, size_t ws_size,
                              hipStream_t stream) {
  const int* idx      = (const int*)d_in[0];
  const float* W_emb  = (const float*)d_in[1];
  const float* pos    = (const float*)d_in[2];
  const float* ln1_s  = (const float*)d_in[3];
  const float* ln1_b  = (const float*)d_in[4];
  const float* qkv_w  = (const float*)d_in[5];
  const float* proj_w = (const float*)d_in[6];
  const float* ln2_s  = (const float*)d_in[7];
  const float* ln2_b  = (const float*)d_in[8];
  const float* gate_w = (const float*)d_in[9];
  const float* up_w   = (const float*)d_in[10];
  const float* down_w = (const float*)d_in[11];
  const float* lnf_s  = (const float*)d_in[12];
  const float* lnf_b  = (const float*)d_in[13];
  float* out = (float*)d_out;

  float* x   = (float*)d_ws;                  // [2048,512]
  float* h   = x + (size_t)ROWS * E_SZ;       // [2048,512]
  float* qkv = h + (size_t)ROWS * E_SZ;       // [2048,1536]
  float* o   = qkv + (size_t)ROWS * 3 * E_SZ; // [2048,512]
  float* g   = o + (size_t)ROWS * E_SZ;       // [2048,1365]
  float* u   = g + (size_t)ROWS * HID_SZ;     // [2048,1365]

  embed_kernel<<<ROWS, 128, 0, stream>>>(idx, W_emb, pos, x);

  for (int l = 0; l < L_N; ++l) {
    ln_kernel<<<ROWS, 256, 0, stream>>>(x, h, ln1_s + l * E_SZ, ln1_b + l * E_SZ);
    gemm_kernel<false, false><<<dim3(12, 16), 256, 0, stream>>>(
        h, qkv_w + (size_t)l * E_SZ * 3 * E_SZ, qkv, nullptr, ROWS, 3 * E_SZ, E_SZ);
    attn_kernel<<<B_SZ * H_N * T_SZ, 64, 0, stream>>>(qkv, o);
    gemm_kernel<false, true><<<dim3(4, 16), 256, 0, stream>>>(
        o, proj_w + (size_t)l * E_SZ * E_SZ, x, x, ROWS, E_SZ, E_SZ);
    ln_kernel<<<ROWS, 256, 0, stream>>>(x, h, ln2_s + l * E_SZ, ln2_b + l * E_SZ);
    gemm_kernel<false, false><<<dim3(11, 16), 256, 0, stream>>>(
        h, gate_w + (size_t)l * E_SZ * HID_SZ, g, nullptr, ROWS, HID_SZ, E_SZ);
    gemm_kernel<false, false><<<dim3(11, 16), 256, 0, stream>>>(
        h, up_w + (size_t)l * E_SZ * HID_SZ, u, nullptr, ROWS, HID_SZ, E_SZ);
    swiglu_kernel<<<(ROWS * HID_SZ + 255) / 256, 256, 0, stream>>>(g, u, ROWS * HID_SZ);
    gemm_kernel<false, true><<<dim3(4, 16), 256, 0, stream>>>(
        g, down_w + (size_t)l * HID_SZ * E_SZ, x, x, ROWS, E_SZ, HID_SZ);
  }

  ln_kernel<<<ROWS, 256, 0, stream>>>(x, h, lnf_s, lnf_b);
  gemm_kernel<true, false><<<dim3((V_SZ + 127) / 128, 16), 256, 0, stream>>>(
      h, W_emb, out, nullptr, ROWS, V_SZ, E_SZ);
}

// Round 2
// 4243.816 us; speedup vs baseline: 3.3880x; 3.3880x over previous
//
#include <hip/hip_runtime.h>
#include <hip/hip_bf16.h>
#include <math.h>

#define V_SZ 50257
#define V_PAD 50304
#define E_SZ 512
#define H_N 8
#define L_N 8
#define HID_SZ 1365
#define HID_PAD 1408
#define T_SZ 1024
#define B_SZ 2
#define HD_SZ 64
#define ROWS (B_SZ * T_SZ)   // 2048

typedef short bf16x8 __attribute__((ext_vector_type(8)));
typedef float f32x4 __attribute__((ext_vector_type(4)));

// ---------------------------------------------------------------------------
// Embedding: x[b,t,:] = W_emb[idx[b,t],:] + pos_emb[t,:]   (f32 out)
// ---------------------------------------------------------------------------
__global__ __launch_bounds__(128) void embed_kernel(
    const int* __restrict__ idx, const float* __restrict__ W,
    const float* __restrict__ P, float* __restrict__ x) {
  const int bt = blockIdx.x;
  const int t = bt & (T_SZ - 1);
  const int id = idx[bt];
  const int e = threadIdx.x * 4;
  float4 w = *(const float4*)(W + (size_t)id * E_SZ + e);
  float4 p = *(const float4*)(P + (size_t)t * E_SZ + e);
  float4 r;
  r.x = w.x + p.x; r.y = w.y + p.y; r.z = w.z + p.z; r.w = w.w + p.w;
  *(float4*)(x + (size_t)bt * E_SZ + e) = r;
}

// ---------------------------------------------------------------------------
// LayerNorm over E=512, f32 in -> bf16 out. One block (256 thr) per row.
// ---------------------------------------------------------------------------
__global__ __launch_bounds__(256) void ln_kernel(
    const float* __restrict__ in, __hip_bfloat16* __restrict__ out,
    const float* __restrict__ sc, const float* __restrict__ bi) {
  const int row = blockIdx.x;
  const int tid = threadIdx.x;
  const float2 v = *(const float2*)(in + (size_t)row * E_SZ + tid * 2);
  float s = v.x + v.y;
#pragma unroll
  for (int o = 32; o; o >>= 1) s += __shfl_xor(s, o);
  __shared__ float w1[4], w2[4];
  if ((tid & 63) == 0) w1[tid >> 6] = s;
  __syncthreads();
  const float mean = (w1[0] + w1[1] + w1[2] + w1[3]) * (1.f / 512.f);
  const float d0 = v.x - mean, d1 = v.y - mean;
  float q = d0 * d0 + d1 * d1;
#pragma unroll
  for (int o = 32; o; o >>= 1) q += __shfl_xor(q, o);
  if ((tid & 63) == 0) w2[tid >> 6] = q;
  __syncthreads();
  const float var = (w2[0] + w2[1] + w2[2] + w2[3]) * (1.f / 512.f);
  const float inv = rsqrtf(var + 1e-5f);
  const float2 sv = *(const float2*)(sc + tid * 2);
  const float2 bv = *(const float2*)(bi + tid * 2);
  __hip_bfloat162 ov;
  ov.x = __float2bfloat16(d0 * inv * sv.x + bv.x);
  ov.y = __float2bfloat16(d1 * inv * sv.y + bv.y);
  *(__hip_bfloat162*)(out + (size_t)row * E_SZ + tid * 2) = ov;
}

// ---------------------------------------------------------------------------
// Weight prep: W_emb [V][512] f32 -> [V_PAD][512] bf16 (zero-padded rows)
// ---------------------------------------------------------------------------
__global__ __launch_bounds__(256) void convert_wemb(
    const float* __restrict__ W, __hip_bfloat16* __restrict__ Wb) {
  const int tid = blockIdx.x * 256 + threadIdx.x;   // V_PAD*512/8 threads
  const int row = tid >> 6;
  const int c = (tid & 63) * 8;
  union { __hip_bfloat16 h[8]; int4 v; } u;
  if (row < V_SZ) {
    const float* p = W + (size_t)row * E_SZ + c;
#pragma unroll
    for (int j = 0; j < 8; ++j) u.h[j] = __float2bfloat16(p[j]);
  } else {
#pragma unroll
    for (int j = 0; j < 8; ++j) u.h[j] = __float2bfloat16(0.f);
  }
  *(int4*)(Wb + (size_t)row * E_SZ + c) = u.v;
}

// ---------------------------------------------------------------------------
// Transpose+convert: in [K][N] f32 -> out [Npad][Kpad] bf16, out[n][k]=in[k][n]
// grid (Npad/32, Kpad/32), 256 threads.
// ---------------------------------------------------------------------------
__global__ __launch_bounds__(256) void transp_convert(
    const float* __restrict__ in, __hip_bfloat16* __restrict__ out,
    int K, int N, int Kpad) {
  __shared__ float tile[32][33];
  const int tx = threadIdx.x & 31, ty = threadIdx.x >> 5;   // ty 0..7
  const int n0 = blockIdx.x * 32, k0 = blockIdx.y * 32;
#pragma unroll
  for (int i = 0; i < 4; ++i) {
    const int k = k0 + ty + i * 8, n = n0 + tx;
    tile[ty + i * 8][tx] = (k < K && n < N) ? in[(size_t)k * N + n] : 0.f;
  }
  __syncthreads();
#pragma unroll
  for (int i = 0; i < 4; ++i) {
    const int n = n0 + ty + i * 8, kk = k0 + tx;
    out[(size_t)n * Kpad + kk] = __float2bfloat16(tile[tx][ty + i * 8]);
  }
}

// ---------------------------------------------------------------------------
// bf16 MFMA GEMM (m97 structure): C[M,N](f32) = A[M,K](bf16) @ B^T, where
// B is stored [Npad][K] bf16 row-major. 128x128 tile, BK=32, 4 waves,
// global_load_lds width-16 staging, 16x16x32 MFMA, 4x4 frags/wave.
// ---------------------------------------------------------------------------
template <bool RES, bool BOUND>
__global__ __launch_bounds__(256) void mfma_gemm(
    const __hip_bfloat16* __restrict__ A, const __hip_bfloat16* __restrict__ B,
    float* __restrict__ C, const float* __restrict__ R, int N, int K) {
  __shared__ char lds[16384];          // As [128][32]bf16 | Bs [128][32]bf16
  const int tid = threadIdx.x;
  const int lane = tid & 63, w = tid >> 6;
  const int wr = w >> 1, wc = w & 1;
  const int m0 = blockIdx.y * 128, n0 = blockIdx.x * 128;
  const size_t SA = (size_t)K * 2;     // row stride bytes (A and B share K)

  f32x4 acc[4][4] = {};
  char* As = lds;
  char* Bs = lds + 8192;
  const char* Ab = (const char*)A + (size_t)m0 * SA;
  const char* Bb = (const char*)B + (size_t)n0 * SA;

  const int r = lane >> 2, cb = (lane & 3) * 16;
  for (int k0 = 0; k0 < K; k0 += 32) {
    // stage 16KB: wave w stages chunks 2w, 2w+1 of A and of B (1KB each)
#pragma unroll
    for (int cc2 = 0; cc2 < 2; ++cc2) {
      const int c = w * 2 + cc2;
      const char* ga = Ab + (size_t)(c * 16 + r) * SA + k0 * 2 + cb;
      __builtin_amdgcn_global_load_lds(
          (const __attribute__((address_space(1))) unsigned int*)ga,
          (__attribute__((address_space(3))) unsigned int*)(As + c * 1024),
          16, 0, 0);
      const char* gb = Bb + (size_t)(c * 16 + r) * SA + k0 * 2 + cb;
      __builtin_amdgcn_global_load_lds(
          (const __attribute__((address_space(1))) unsigned int*)gb,
          (__attribute__((address_space(3))) unsigned int*)(Bs + c * 1024),
          16, 0, 0);
    }
    __syncthreads();
    bf16x8 a[4], b[4];
    const int kb = (lane >> 4) * 16;
#pragma unroll
    for (int i = 0; i < 4; ++i) {
      a[i] = *(const bf16x8*)(As + (wr * 64 + i * 16 + (lane & 15)) * 64 + kb);
      b[i] = *(const bf16x8*)(Bs + (wc * 64 + i * 16 + (lane & 15)) * 64 + kb);
    }
#pragma unroll
    for (int i = 0; i < 4; ++i)
#pragma unroll
      for (int j = 0; j < 4; ++j)
        acc[i][j] = __builtin_amdgcn_mfma_f32_16x16x32_bf16(a[i], b[j], acc[i][j], 0, 0, 0);
    __syncthreads();
  }

  // C/D layout: col = lane&15, row = (lane>>4)*4 + reg   [m89/m91 verified]
  const int cr = (lane >> 4) * 4, ccol = lane & 15;
#pragma unroll
  for (int i = 0; i < 4; ++i) {
#pragma unroll
    for (int j = 0; j < 4; ++j) {
      const int n = n0 + wc * 64 + j * 16 + ccol;
      if (BOUND && n >= N) continue;
#pragma unroll
      for (int rr = 0; rr < 4; ++rr) {
        const int m = m0 + wr * 64 + i * 16 + cr + rr;
        float v = acc[i][j][rr];
        if (RES) v += R[(size_t)m * N + n];
        C[(size_t)m * N + n] = v;
      }
    }
  }
}

// ---------------------------------------------------------------------------
// Attention: one wave per (b, h, query row i). f32 in (qkv), bf16 out.
// ---------------------------------------------------------------------------
__global__ __launch_bounds__(64) void attn_kernel(
    const float* __restrict__ qkv, __hip_bfloat16* __restrict__ o) {
  const int bid = blockIdx.x;
  const int i = bid & (T_SZ - 1);
  const int h = (bid >> 10) & (H_N - 1);
  const int b = bid >> 13;
  const int lane = threadIdx.x;

  __shared__ __align__(16) float qs[64];
  __shared__ __align__(16) float sc[T_SZ];

  const size_t rowQ = ((size_t)(b * T_SZ + i)) * (3 * E_SZ) + h * HD_SZ;
  qs[lane] = qkv[rowQ + lane];
  __syncthreads();

  const float slope = exp2f(-(float)(h + 1));
  float mx = -1e30f;
  for (int j = lane; j <= i; j += 64) {
    const float* kr = qkv + ((size_t)(b * T_SZ + j)) * (3 * E_SZ) + E_SZ + h * HD_SZ;
    float dot = 0.f;
#pragma unroll
    for (int c = 0; c < 16; ++c) {
      float4 k4 = *(const float4*)(kr + c * 4);
      float4 q4 = *(const float4*)(qs + c * 4);
      dot += q4.x * k4.x + q4.y * k4.y + q4.z * k4.z + q4.w * k4.w;
    }
    float s = dot * 0.125f + slope * (float)(i - j);
    sc[j] = s;
    mx = fmaxf(mx, s);
  }
#pragma unroll
  for (int off = 32; off; off >>= 1) mx = fmaxf(mx, __shfl_xor(mx, off));
  float sum = 0.f;
  for (int j = lane; j <= i; j += 64) {
    float e = expf(sc[j] - mx);
    sc[j] = e;
    sum += e;
  }
#pragma unroll
  for (int off = 32; off; off >>= 1) sum += __shfl_xor(sum, off);
  __syncthreads();
  const float inv = 1.f / sum;

  float acc = 0.f;
  const float* vbase = qkv + (size_t)(b * T_SZ) * (3 * E_SZ) + 2 * E_SZ + h * HD_SZ + lane;
  for (int j = 0; j <= i; ++j) {
    acc += sc[j] * vbase[(size_t)j * (3 * E_SZ)];
  }
  o[((size_t)(b * T_SZ + i)) * E_SZ + h * HD_SZ + lane] = __float2bfloat16(acc * inv);
}

// ---------------------------------------------------------------------------
// SwiGLU: g,u f32 [2048][1365] -> g_bf bf16 [2048][1408] (zero-padded cols)
// ---------------------------------------------------------------------------
__global__ __launch_bounds__(256) void swiglu_kernel(
    const float* __restrict__ g, const float* __restrict__ u,
    __hip_bfloat16* __restrict__ gb) {
  const int tid = blockIdx.x * 256 + threadIdx.x;   // ROWS * 352
  const int row = tid / 352, c0 = (tid % 352) * 4;
  union { __hip_bfloat16 h[4]; short4 v; } ov;
#pragma unroll
  for (int j = 0; j < 4; ++j) {
    const int c = c0 + j;
    float val = 0.f;
    if (c < HID_SZ) {
      const float gv = g[(size_t)row * HID_SZ + c];
      val = gv / (1.f + expf(-gv)) * u[(size_t)row * HID_SZ + c];
    }
    ov.h[j] = __float2bfloat16(val);
  }
  *(short4*)(gb + (size_t)row * HID_PAD + c0) = ov.v;
}

// ---------------------------------------------------------------------------
extern "C" void kernel_launch(void* const* d_in, const int* in_sizes, int n_in,
                              void* d_out, int out_size, void* d_ws, size_t ws_size,
                              hipStream_t stream) {
  const int* idx      = (const int*)d_in[0];
  const float* W_emb  = (const float*)d_in[1];
  const float* pos    = (const float*)d_in[2];
  const float* ln1_s  = (const float*)d_in[3];
  const float* ln1_b  = (const float*)d_in[4];
  const float* qkv_w  = (const float*)d_in[5];
  const float* proj_w = (const float*)d_in[6];
  const float* ln2_s  = (const float*)d_in[7];
  const float* ln2_b  = (const float*)d_in[8];
  const float* gate_w = (const float*)d_in[9];
  const float* up_w   = (const float*)d_in[10];
  const float* down_w = (const float*)d_in[11];
  const float* lnf_s  = (const float*)d_in[12];
  const float* lnf_b  = (const float*)d_in[13];
  float* out = (float*)d_out;

  char* p = (char*)d_ws;
  auto alloc = [&](size_t bytes) { char* q = p; p += (bytes + 255) & ~255ULL; return q; };
  float* x    = (float*)alloc((size_t)ROWS * E_SZ * 4);
  float* qkv  = (float*)alloc((size_t)ROWS * 3 * E_SZ * 4);
  float* g    = (float*)alloc((size_t)ROWS * HID_SZ * 4);
  float* u    = (float*)alloc((size_t)ROWS * HID_SZ * 4);
  __hip_bfloat16* h_bf  = (__hip_bfloat16*)alloc((size_t)ROWS * E_SZ * 2);
  __hip_bfloat16* o_bf  = (__hip_bfloat16*)alloc((size_t)ROWS * E_SZ * 2);
  __hip_bfloat16* g_bf  = (__hip_bfloat16*)alloc((size_t)ROWS * HID_PAD * 2);
  __hip_bfloat16* Wb    = (__hip_bfloat16*)alloc((size_t)V_PAD * E_SZ * 2);
  __hip_bfloat16* qkvwb = (__hip_bfloat16*)alloc((size_t)L_N * 3 * E_SZ * E_SZ * 2);
  __hip_bfloat16* projwb= (__hip_bfloat16*)alloc((size_t)L_N * E_SZ * E_SZ * 2);
  __hip_bfloat16* gatewb= (__hip_bfloat16*)alloc((size_t)L_N * HID_PAD * E_SZ * 2);
  __hip_bfloat16* upwb  = (__hip_bfloat16*)alloc((size_t)L_N * HID_PAD * E_SZ * 2);
  __hip_bfloat16* downwb= (__hip_bfloat16*)alloc((size_t)L_N * E_SZ * HID_PAD * 2);

  // ---- weight prep (deterministic, every launch) ----
  convert_wemb<<<(V_PAD * E_SZ / 8 + 255) / 256, 256, 0, stream>>>(W_emb, Wb);
  for (int l = 0; l < L_N; ++l) {
    transp_convert<<<dim3(3 * E_SZ / 32, E_SZ / 32), 256, 0, stream>>>(
        qkv_w + (size_t)l * E_SZ * 3 * E_SZ, qkvwb + (size_t)l * 3 * E_SZ * E_SZ,
        E_SZ, 3 * E_SZ, E_SZ);
    transp_convert<<<dim3(E_SZ / 32, E_SZ / 32), 256, 0, stream>>>(
        proj_w + (size_t)l * E_SZ * E_SZ, projwb + (size_t)l * E_SZ * E_SZ,
        E_SZ, E_SZ, E_SZ);
    transp_convert<<<dim3(HID_PAD / 32, E_SZ / 32), 256, 0, stream>>>(
        gate_w + (size_t)l * E_SZ * HID_SZ, gatewb + (size_t)l * HID_PAD * E_SZ,
        E_SZ, HID_SZ, E_SZ);
    transp_convert<<<dim3(HID_PAD / 32, E_SZ / 32), 256, 0, stream>>>(
        up_w + (size_t)l * E_SZ * HID_SZ, upwb + (size_t)l * HID_PAD * E_SZ,
        E_SZ, HID_SZ, E_SZ);
    transp_convert<<<dim3(E_SZ / 32, HID_PAD / 32), 256, 0, stream>>>(
        down_w + (size_t)l * HID_SZ * E_SZ, downwb + (size_t)l * E_SZ * HID_PAD,
        HID_SZ, E_SZ, HID_PAD);
  }

  embed_kernel<<<ROWS, 128, 0, stream>>>(idx, W_emb, pos, x);

  for (int l = 0; l < L_N; ++l) {
    ln_kernel<<<ROWS, 256, 0, stream>>>(x, h_bf, ln1_s + l * E_SZ, ln1_b + l * E_SZ);
    mfma_gemm<false, false><<<dim3(12, 16), 256, 0, stream>>>(
        h_bf, qkvwb + (size_t)l * 3 * E_SZ * E_SZ, qkv, nullptr, 3 * E_SZ, E_SZ);
    attn_kernel<<<B_SZ * H_N * T_SZ, 64, 0, stream>>>(qkv, o_bf);
    mfma_gemm<true, false><<<dim3(4, 16), 256, 0, stream>>>(
        o_bf, projwb + (size_t)l * E_SZ * E_SZ, x, x, E_SZ, E_SZ);
    ln_kernel<<<ROWS, 256, 0, stream>>>(x, h_bf, ln2_s + l * E_SZ, ln2_b + l * E_SZ);
    mfma_gemm<false, true><<<dim3(11, 16), 256, 0, stream>>>(
        h_bf, gatewb + (size_t)l * HID_PAD * E_SZ, g, nullptr, HID_SZ, E_SZ);
    mfma_gemm<false, true><<<dim3(11, 16), 256, 0, stream>>>(
        h_bf, upwb + (size_t)l * HID_PAD * E_SZ, u, nullptr, HID_SZ, E_SZ);
    swiglu_kernel<<<(ROWS * 352 + 255) / 256, 256, 0, stream>>>(g, u, g_bf);
    mfma_gemm<true, false><<<dim3(4, 16), 256, 0, stream>>>(
        g_bf, downwb + (size_t)l * E_SZ * HID_PAD, x, x, E_SZ, HID_PAD);
  }

  ln_kernel<<<ROWS, 256, 0, stream>>>(x, h_bf, lnf_s, lnf_b);
  mfma_gemm<false, true><<<dim3(V_PAD / 128, 16), 256, 0, stream>>>(
      h_bf, Wb, out, nullptr, V_SZ, E_SZ);
}

// Round 4
// 1653.206 us; speedup vs baseline: 8.6969x; 2.5670x over previous
//
#include <hip/hip_runtime.h>
#include <hip/hip_bf16.h>
#include <math.h>

#define V_SZ 50257
#define V_PAD 50304
#define E_SZ 512
#define H_N 8
#define L_N 8
#define HID_SZ 1365
#define HID_PAD 1408
#define T_SZ 1024
#define B_SZ 2
#define HD_SZ 64
#define ROWS (B_SZ * T_SZ)   // 2048

typedef short bf16x8 __attribute__((ext_vector_type(8)));
typedef float f32x4 __attribute__((ext_vector_type(4)));
typedef float f32x16 __attribute__((ext_vector_type(16)));

// ---------------------------------------------------------------------------
// Embedding: x[b,t,:] = W_emb[idx[b,t],:] + pos_emb[t,:]   (f32 out)
// ---------------------------------------------------------------------------
__global__ __launch_bounds__(128) void embed_kernel(
    const int* __restrict__ idx, const float* __restrict__ W,
    const float* __restrict__ P, float* __restrict__ x) {
  const int bt = blockIdx.x;
  const int t = bt & (T_SZ - 1);
  const int id = idx[bt];
  const int e = threadIdx.x * 4;
  float4 w = *(const float4*)(W + (size_t)id * E_SZ + e);
  float4 p = *(const float4*)(P + (size_t)t * E_SZ + e);
  float4 r;
  r.x = w.x + p.x; r.y = w.y + p.y; r.z = w.z + p.z; r.w = w.w + p.w;
  *(float4*)(x + (size_t)bt * E_SZ + e) = r;
}

// ---------------------------------------------------------------------------
// LayerNorm over E=512, f32 in -> bf16 out. One block (256 thr) per row.
// ---------------------------------------------------------------------------
__global__ __launch_bounds__(256) void ln_kernel(
    const float* __restrict__ in, __hip_bfloat16* __restrict__ out,
    const float* __restrict__ sc, const float* __restrict__ bi) {
  const int row = blockIdx.x;
  const int tid = threadIdx.x;
  const float2 v = *(const float2*)(in + (size_t)row * E_SZ + tid * 2);
  float s = v.x + v.y;
#pragma unroll
  for (int o = 32; o; o >>= 1) s += __shfl_xor(s, o);
  __shared__ float w1[4], w2[4];
  if ((tid & 63) == 0) w1[tid >> 6] = s;
  __syncthreads();
  const float mean = (w1[0] + w1[1] + w1[2] + w1[3]) * (1.f / 512.f);
  const float d0 = v.x - mean, d1 = v.y - mean;
  float q = d0 * d0 + d1 * d1;
#pragma unroll
  for (int o = 32; o; o >>= 1) q += __shfl_xor(q, o);
  if ((tid & 63) == 0) w2[tid >> 6] = q;
  __syncthreads();
  const float var = (w2[0] + w2[1] + w2[2] + w2[3]) * (1.f / 512.f);
  const float inv = rsqrtf(var + 1e-5f);
  const float2 sv = *(const float2*)(sc + tid * 2);
  const float2 bv = *(const float2*)(bi + tid * 2);
  __hip_bfloat162 ov;
  ov.x = __float2bfloat16(d0 * inv * sv.x + bv.x);
  ov.y = __float2bfloat16(d1 * inv * sv.y + bv.y);
  *(__hip_bfloat162*)(out + (size_t)row * E_SZ + tid * 2) = ov;
}

// ---------------------------------------------------------------------------
// Weight prep: W_emb [V][512] f32 -> [V_PAD][512] bf16 (zero-padded rows)
// ---------------------------------------------------------------------------
__global__ __launch_bounds__(256) void convert_wemb(
    const float* __restrict__ W, __hip_bfloat16* __restrict__ Wb) {
  const int tid = blockIdx.x * 256 + threadIdx.x;
  const int row = tid >> 6;
  const int c = (tid & 63) * 8;
  union { __hip_bfloat16 h[8]; int4 v; } u;
  if (row < V_SZ) {
    const float* p = W + (size_t)row * E_SZ + c;
#pragma unroll
    for (int j = 0; j < 8; ++j) u.h[j] = __float2bfloat16(p[j]);
  } else {
#pragma unroll
    for (int j = 0; j < 8; ++j) u.h[j] = __float2bfloat16(0.f);
  }
  *(int4*)(Wb + (size_t)row * E_SZ + c) = u.v;
}

// ---------------------------------------------------------------------------
// Transpose+convert: in [K][N] f32 -> out [Npad][Kpad] bf16
// ---------------------------------------------------------------------------
__global__ __launch_bounds__(256) void transp_convert(
    const float* __restrict__ in, __hip_bfloat16* __restrict__ out,
    int K, int N, int Kpad) {
  __shared__ float tile[32][33];
  const int tx = threadIdx.x & 31, ty = threadIdx.x >> 5;
  const int n0 = blockIdx.x * 32, k0 = blockIdx.y * 32;
#pragma unroll
  for (int i = 0; i < 4; ++i) {
    const int k = k0 + ty + i * 8, n = n0 + tx;
    tile[ty + i * 8][tx] = (k < K && n < N) ? in[(size_t)k * N + n] : 0.f;
  }
  __syncthreads();
#pragma unroll
  for (int i = 0; i < 4; ++i) {
    const int n = n0 + ty + i * 8, kk = k0 + tx;
    out[(size_t)n * Kpad + kk] = __float2bfloat16(tile[tx][ty + i * 8]);
  }
}

// ---------------------------------------------------------------------------
// bf16 MFMA GEMM (m97 structure): C[M,N] = A[M,K](bf16) @ B^T.
// OBF: store bf16 instead of f32.
// ---------------------------------------------------------------------------
template <bool RES, bool BOUND, bool OBF>
__global__ __launch_bounds__(256) void mfma_gemm(
    const __hip_bfloat16* __restrict__ A, const __hip_bfloat16* __restrict__ B,
    float* __restrict__ C, const float* __restrict__ R, int N, int K) {
  __shared__ char lds[16384];
  const int tid = threadIdx.x;
  const int lane = tid & 63, w = tid >> 6;
  const int wr = w >> 1, wc = w & 1;
  const int m0 = blockIdx.y * 128, n0 = blockIdx.x * 128;
  const size_t SA = (size_t)K * 2;

  f32x4 acc[4][4] = {};
  char* As = lds;
  char* Bs = lds + 8192;
  const char* Ab = (const char*)A + (size_t)m0 * SA;
  const char* Bb = (const char*)B + (size_t)n0 * SA;

  const int r = lane >> 2, cb = (lane & 3) * 16;
  for (int k0 = 0; k0 < K; k0 += 32) {
#pragma unroll
    for (int cc2 = 0; cc2 < 2; ++cc2) {
      const int c = w * 2 + cc2;
      const char* ga = Ab + (size_t)(c * 16 + r) * SA + k0 * 2 + cb;
      __builtin_amdgcn_global_load_lds(
          (const __attribute__((address_space(1))) unsigned int*)ga,
          (__attribute__((address_space(3))) unsigned int*)(As + c * 1024),
          16, 0, 0);
      const char* gb = Bb + (size_t)(c * 16 + r) * SA + k0 * 2 + cb;
      __builtin_amdgcn_global_load_lds(
          (const __attribute__((address_space(1))) unsigned int*)gb,
          (__attribute__((address_space(3))) unsigned int*)(Bs + c * 1024),
          16, 0, 0);
    }
    __syncthreads();
    bf16x8 a[4], b[4];
    const int kb = (lane >> 4) * 16;
#pragma unroll
    for (int i = 0; i < 4; ++i) {
      a[i] = *(const bf16x8*)(As + (wr * 64 + i * 16 + (lane & 15)) * 64 + kb);
      b[i] = *(const bf16x8*)(Bs + (wc * 64 + i * 16 + (lane & 15)) * 64 + kb);
    }
#pragma unroll
    for (int i = 0; i < 4; ++i)
#pragma unroll
      for (int j = 0; j < 4; ++j)
        acc[i][j] = __builtin_amdgcn_mfma_f32_16x16x32_bf16(a[i], b[j], acc[i][j], 0, 0, 0);
    __syncthreads();
  }

  const int cr = (lane >> 4) * 4, ccol = lane & 15;
#pragma unroll
  for (int i = 0; i < 4; ++i) {
#pragma unroll
    for (int j = 0; j < 4; ++j) {
      const int n = n0 + wc * 64 + j * 16 + ccol;
      if (BOUND && n >= N) continue;
#pragma unroll
      for (int rr = 0; rr < 4; ++rr) {
        const int m = m0 + wr * 64 + i * 16 + cr + rr;
        float v = acc[i][j][rr];
        if (RES) v += R[(size_t)m * N + n];
        if (OBF) ((__hip_bfloat16*)C)[(size_t)m * N + n] = __float2bfloat16(v);
        else C[(size_t)m * N + n] = v;
      }
    }
  }
}

// ---------------------------------------------------------------------------
// Flash attention with 32x32x16 MFMA, swapped operands.
// Block = 128 thr (2 waves), each wave owns a 32-row Q-tile; block covers 64
// q-rows of one (b,h). KV streamed in 64-wide chunks staged to swizzled LDS.
// S^T = mfma(K,Q): lane holds q=lane&31, kv=(r&3)+8(r>>2)+4*(lane>>5).
// O^T = mfma(VT,P): lane holds q=lane&31, d likewise -> rescale lane-uniform.
// ---------------------------------------------------------------------------
__global__ __launch_bounds__(128) void attn_mfma_kernel(
    const __hip_bfloat16* __restrict__ qkv, __hip_bfloat16* __restrict__ o) {
  const int bid = blockIdx.x;
  const int qb = bid & 15;
  const int h = (bid >> 4) & 7;
  const int b = bid >> 7;
  const int tid = threadIdx.x;
  const int w = tid >> 6, lane = tid & 63;
  const int l31 = lane & 31, hi = lane >> 5;
  const int q0w = qb * 64 + 32 * w;
  const float slope = exp2f(-(float)(h + 1));
  const int rowstride = 3 * E_SZ;

  __shared__ char lds[16384];
  char* Kl = lds;
  char* Vl = lds + 8192;

  bf16x8 qf[4];
  {
    const __hip_bfloat16* qrow = qkv + (size_t)(b * T_SZ + q0w + l31) * rowstride + h * HD_SZ;
#pragma unroll
    for (int dblk = 0; dblk < 4; ++dblk)
      qf[dblk] = *(const bf16x8*)(qrow + dblk * 16 + hi * 8);
  }

  f32x16 oacc[2] = {};
  float m = -INFINITY, lsum = 0.f;

  for (int c = 0; c <= qb; ++c) {
    const int j0c = c * 64;
    {  // stage K [64 kv][64 d] bf16, swizzled byte ^= ((kv&7)<<4)
      const int j = tid >> 1, half = tid & 1;
      const __hip_bfloat16* src = qkv + (size_t)(b * T_SZ + j0c + j) * rowstride + E_SZ + h * HD_SZ + half * 32;
#pragma unroll
      for (int u2 = 0; u2 < 4; ++u2) {
        int4 v = *(const int4*)(src + u2 * 8);
        const int d0 = half * 32 + u2 * 8;
        *(int4*)(Kl + j * 128 + ((2 * d0) ^ ((j & 7) << 4))) = v;
      }
    }
    {  // stage VT [64 d][64 j] bf16 (transposed), swizzled byte ^= ((d&7)<<4)
      const int jp = tid >> 2, quarter = tid & 3;
      const int j0 = jp * 2, d0 = quarter * 16;
      const __hip_bfloat16* s0 = qkv + (size_t)(b * T_SZ + j0c + j0) * rowstride + 2 * E_SZ + h * HD_SZ + d0;
      const __hip_bfloat16* s1 = s0 + rowstride;
      union { int4 v[2]; unsigned short us[16]; } aa, bb;
      aa.v[0] = *(const int4*)(s0);  aa.v[1] = *(const int4*)(s0 + 8);
      bb.v[0] = *(const int4*)(s1);  bb.v[1] = *(const int4*)(s1 + 8);
#pragma unroll
      for (int e = 0; e < 16; ++e) {
        const int d = d0 + e;
        const unsigned wv = (unsigned)aa.us[e] | ((unsigned)bb.us[e] << 16);
        *(unsigned*)(Vl + d * 128 + ((2 * j0) ^ ((d & 7) << 4))) = wv;
      }
    }
    __syncthreads();
#pragma unroll
    for (int s = 0; s < 2; ++s) {
      const int j0 = j0c + 32 * s;
      if (j0 <= q0w + 31) {
        f32x16 sacc = {};
        const int jrow = 32 * s + l31;
#pragma unroll
        for (int dblk = 0; dblk < 4; ++dblk) {
          bf16x8 kf = *(const bf16x8*)(Kl + jrow * 128 + ((dblk * 32 + hi * 16) ^ ((jrow & 7) << 4)));
          sacc = __builtin_amdgcn_mfma_f32_32x32x16_bf16(kf, qf[dblk], sacc, 0, 0, 0);
        }
        const int qg = q0w + l31;
        float p[16];
        float tmax = -1e30f;
#pragma unroll
        for (int r = 0; r < 16; ++r) {
          const int jg = j0 + (r & 3) + 8 * (r >> 2) + 4 * hi;
          const float sv = (jg > qg) ? -1e9f : (sacc[r] * 0.125f + slope * (float)(qg - jg));
          p[r] = sv;
          tmax = fmaxf(tmax, sv);
        }
        tmax = fmaxf(tmax, __shfl_xor(tmax, 32));
        const float mnew = fmaxf(m, tmax);
        const float corr = __expf(m - mnew);
        float tsum = 0.f;
#pragma unroll
        for (int r = 0; r < 16; ++r) {
          p[r] = __expf(p[r] - mnew);
          tsum += p[r];
        }
        tsum += __shfl_xor(tsum, 32);
        lsum = lsum * corr + tsum;
        m = mnew;
#pragma unroll
        for (int dt = 0; dt < 2; ++dt)
#pragma unroll
          for (int r = 0; r < 16; ++r) oacc[dt][r] *= corr;
        // pack P into bf16 A/B-frag layout: lane needs j = jb*16 + 8*hi + e
        unsigned wds[8];
#pragma unroll
        for (int k = 0; k < 8; ++k) {
          union { __hip_bfloat16 hh[2]; unsigned u; } pk_;
          pk_.hh[0] = __float2bfloat16(p[2 * k]);
          pk_.hh[1] = __float2bfloat16(p[2 * k + 1]);
          wds[k] = pk_.u;
        }
        bf16x8 pfrag[2];
#pragma unroll
        for (int jb = 0; jb < 2; ++jb) {
          const unsigned w0 = wds[4 * jb + 0], w1 = wds[4 * jb + 1];
          const unsigned w2 = wds[4 * jb + 2], w3 = wds[4 * jb + 3];
          const unsigned x2 = (unsigned)__shfl_xor((int)w2, 32);
          const unsigned x3 = (unsigned)__shfl_xor((int)w3, 32);
          const unsigned x0 = (unsigned)__shfl_xor((int)w0, 32);
          const unsigned x1 = (unsigned)__shfl_xor((int)w1, 32);
          union { unsigned u[4]; bf16x8 v; } pf;
          pf.u[0] = hi ? x2 : w0;
          pf.u[1] = hi ? x3 : w1;
          pf.u[2] = hi ? w2 : x0;
          pf.u[3] = hi ? w3 : x1;
          pfrag[jb] = pf.v;
        }
#pragma unroll
        for (int dt = 0; dt < 2; ++dt) {
          const int row = dt * 32 + l31;
#pragma unroll
          for (int jb = 0; jb < 2; ++jb) {
            // V^T[d=row][j = s*32 + jb*16 + hi*8 + e]: byte = s*64+jb*32+hi*16
            bf16x8 vt = *(const bf16x8*)(Vl + row * 128 + ((s * 64 + jb * 32 + hi * 16) ^ ((row & 7) << 4)));
            oacc[dt] = __builtin_amdgcn_mfma_f32_32x32x16_bf16(vt, pfrag[jb], oacc[dt], 0, 0, 0);
          }
        }
      }
    }
    __syncthreads();
  }
  const float inv = 1.f / lsum;
  __hip_bfloat16* orow = o + (size_t)(b * T_SZ + q0w + l31) * E_SZ + h * HD_SZ;
#pragma unroll
  for (int dt = 0; dt < 2; ++dt) {
#pragma unroll
    for (int g = 0; g < 4; ++g) {
      union { __hip_bfloat16 hh[4]; short4 v; } ov;
#pragma unroll
      for (int e = 0; e < 4; ++e)
        ov.hh[e] = __float2bfloat16(oacc[dt][4 * g + e] * inv);
      *(short4*)(orow + dt * 32 + 4 * hi + 8 * g) = ov.v;
    }
  }
}

// ---------------------------------------------------------------------------
// SwiGLU: g,u f32 -> g_bf bf16 [2048][1408] (zero-padded cols)
// ---------------------------------------------------------------------------
__global__ __launch_bounds__(256) void swiglu_kernel(
    const float* __restrict__ g, const float* __restrict__ u,
    __hip_bfloat16* __restrict__ gb) {
  const int tid = blockIdx.x * 256 + threadIdx.x;
  const int row = tid / 352, c0 = (tid % 352) * 4;
  union { __hip_bfloat16 h[4]; short4 v; } ov;
#pragma unroll
  for (int j = 0; j < 4; ++j) {
    const int c = c0 + j;
    float val = 0.f;
    if (c < HID_SZ) {
      const float gv = g[(size_t)row * HID_SZ + c];
      val = gv / (1.f + expf(-gv)) * u[(size_t)row * HID_SZ + c];
    }
    ov.h[j] = __float2bfloat16(val);
  }
  *(short4*)(gb + (size_t)row * HID_PAD + c0) = ov.v;
}

// ---------------------------------------------------------------------------
extern "C" void kernel_launch(void* const* d_in, const int* in_sizes, int n_in,
                              void* d_out, int out_size, void* d_ws, size_t ws_size,
                              hipStream_t stream) {
  const int* idx      = (const int*)d_in[0];
  const float* W_emb  = (const float*)d_in[1];
  const float* pos    = (const float*)d_in[2];
  const float* ln1_s  = (const float*)d_in[3];
  const float* ln1_b  = (const float*)d_in[4];
  const float* qkv_w  = (const float*)d_in[5];
  const float* proj_w = (const float*)d_in[6];
  const float* ln2_s  = (const float*)d_in[7];
  const float* ln2_b  = (const float*)d_in[8];
  const float* gate_w = (const float*)d_in[9];
  const float* up_w   = (const float*)d_in[10];
  const float* down_w = (const float*)d_in[11];
  const float* lnf_s  = (const float*)d_in[12];
  const float* lnf_b  = (const float*)d_in[13];
  float* out = (float*)d_out;

  char* p = (char*)d_ws;
  auto alloc = [&](size_t bytes) { char* q = p; p += (bytes + 255) & ~255ULL; return q; };
  float* x    = (float*)alloc((size_t)ROWS * E_SZ * 4);
  float* g    = (float*)alloc((size_t)ROWS * HID_SZ * 4);
  float* u    = (float*)alloc((size_t)ROWS * HID_SZ * 4);
  __hip_bfloat16* qkv_bf = (__hip_bfloat16*)alloc((size_t)ROWS * 3 * E_SZ * 2);
  __hip_bfloat16* h_bf  = (__hip_bfloat16*)alloc((size_t)ROWS * E_SZ * 2);
  __hip_bfloat16* o_bf  = (__hip_bfloat16*)alloc((size_t)ROWS * E_SZ * 2);
  __hip_bfloat16* g_bf  = (__hip_bfloat16*)alloc((size_t)ROWS * HID_PAD * 2);
  __hip_bfloat16* Wb    = (__hip_bfloat16*)alloc((size_t)V_PAD * E_SZ * 2);
  __hip_bfloat16* qkvwb = (__hip_bfloat16*)alloc((size_t)L_N * 3 * E_SZ * E_SZ * 2);
  __hip_bfloat16* projwb= (__hip_bfloat16*)alloc((size_t)L_N * E_SZ * E_SZ * 2);
  __hip_bfloat16* gatewb= (__hip_bfloat16*)alloc((size_t)L_N * HID_PAD * E_SZ * 2);
  __hip_bfloat16* upwb  = (__hip_bfloat16*)alloc((size_t)L_N * HID_PAD * E_SZ * 2);
  __hip_bfloat16* downwb= (__hip_bfloat16*)alloc((size_t)L_N * E_SZ * HID_PAD * 2);

  convert_wemb<<<(V_PAD * E_SZ / 8 + 255) / 256, 256, 0, stream>>>(W_emb, Wb);
  for (int l = 0; l < L_N; ++l) {
    transp_convert<<<dim3(3 * E_SZ / 32, E_SZ / 32), 256, 0, stream>>>(
        qkv_w + (size_t)l * E_SZ * 3 * E_SZ, qkvwb + (size_t)l * 3 * E_SZ * E_SZ,
        E_SZ, 3 * E_SZ, E_SZ);
    transp_convert<<<dim3(E_SZ / 32, E_SZ / 32), 256, 0, stream>>>(
        proj_w + (size_t)l * E_SZ * E_SZ, projwb + (size_t)l * E_SZ * E_SZ,
        E_SZ, E_SZ, E_SZ);
    transp_convert<<<dim3(HID_PAD / 32, E_SZ / 32), 256, 0, stream>>>(
        gate_w + (size_t)l * E_SZ * HID_SZ, gatewb + (size_t)l * HID_PAD * E_SZ,
        E_SZ, HID_SZ, E_SZ);
    transp_convert<<<dim3(HID_PAD / 32, E_SZ / 32), 256, 0, stream>>>(
        up_w + (size_t)l * E_SZ * HID_SZ, upwb + (size_t)l * HID_PAD * E_SZ,
        E_SZ, HID_SZ, E_SZ);
    transp_convert<<<dim3(E_SZ / 32, HID_PAD / 32), 256, 0, stream>>>(
        down_w + (size_t)l * HID_SZ * E_SZ, downwb + (size_t)l * E_SZ * HID_PAD,
        HID_SZ, E_SZ, HID_PAD);
  }

  embed_kernel<<<ROWS, 128, 0, stream>>>(idx, W_emb, pos, x);

  for (int l = 0; l < L_N; ++l) {
    ln_kernel<<<ROWS, 256, 0, stream>>>(x, h_bf, ln1_s + l * E_SZ, ln1_b + l * E_SZ);
    mfma_gemm<false, false, true><<<dim3(12, 16), 256, 0, stream>>>(
        h_bf, qkvwb + (size_t)l * 3 * E_SZ * E_SZ, (float*)qkv_bf, nullptr, 3 * E_SZ, E_SZ);
    attn_mfma_kernel<<<B_SZ * H_N * (T_SZ / 64), 128, 0, stream>>>(qkv_bf, o_bf);
    mfma_gemm<true, false, false><<<dim3(4, 16), 256, 0, stream>>>(
        o_bf, projwb + (size_t)l * E_SZ * E_SZ, x, x, E_SZ, E_SZ);
    ln_kernel<<<ROWS, 256, 0, stream>>>(x, h_bf, ln2_s + l * E_SZ, ln2_b + l * E_SZ);
    mfma_gemm<false, true, false><<<dim3(11, 16), 256, 0, stream>>>(
        h_bf, gatewb + (size_t)l * HID_PAD * E_SZ, g, nullptr, HID_SZ, E_SZ);
    mfma_gemm<false, true, false><<<dim3(11, 16), 256, 0, stream>>>(
        h_bf, upwb + (size_t)l * HID_PAD * E_SZ, u, nullptr, HID_SZ, E_SZ);
    swiglu_kernel<<<(ROWS * 352 + 255) / 256, 256, 0, stream>>>(g, u, g_bf);
    mfma_gemm<true, false, false><<<dim3(4, 16), 256, 0, stream>>>(
        g_bf, downwb + (size_t)l * E_SZ * HID_PAD, x, x, E_SZ, HID_PAD);
  }

  ln_kernel<<<ROWS, 256, 0, stream>>>(x, h_bf, lnf_s, lnf_b);
  mfma_gemm<false, true, false><<<dim3(V_PAD / 128, 16), 256, 0, stream>>>(
      h_bf, Wb, out, nullptr, V_SZ, E_SZ);
}

// Round 5
// 1349.819 us; speedup vs baseline: 10.6517x; 1.2248x over previous
//
#include <hip/hip_runtime.h>
#include <hip/hip_bf16.h>
#include <math.h>

#define V_SZ 50257
#define V_PAD 50304
#define E_SZ 512
#define H_N 8
#define L_N 8
#define HID_SZ 1365
#define HID_PAD 1408
#define T_SZ 1024
#define B_SZ 2
#define HD_SZ 64
#define ROWS (B_SZ * T_SZ)   // 2048

typedef short bf16x8 __attribute__((ext_vector_type(8)));
typedef float f32x4 __attribute__((ext_vector_type(4)));
typedef float f32x16 __attribute__((ext_vector_type(16)));

// ---------------------------------------------------------------------------
// Embedding: x[b,t,:] = W_emb[idx[b,t],:] + pos_emb[t,:]   (f32 out)
// ---------------------------------------------------------------------------
__global__ __launch_bounds__(128) void embed_kernel(
    const int* __restrict__ idx, const float* __restrict__ W,
    const float* __restrict__ P, float* __restrict__ x) {
  const int bt = blockIdx.x;
  const int t = bt & (T_SZ - 1);
  const int id = idx[bt];
  const int e = threadIdx.x * 4;
  float4 w = *(const float4*)(W + (size_t)id * E_SZ + e);
  float4 p = *(const float4*)(P + (size_t)t * E_SZ + e);
  float4 r;
  r.x = w.x + p.x; r.y = w.y + p.y; r.z = w.z + p.z; r.w = w.w + p.w;
  *(float4*)(x + (size_t)bt * E_SZ + e) = r;
}

// ---------------------------------------------------------------------------
// LayerNorm over E=512, f32 in -> bf16 out. One block (256 thr) per row.
// ---------------------------------------------------------------------------
__global__ __launch_bounds__(256) void ln_kernel(
    const float* __restrict__ in, __hip_bfloat16* __restrict__ out,
    const float* __restrict__ sc, const float* __restrict__ bi) {
  const int row = blockIdx.x;
  const int tid = threadIdx.x;
  const float2 v = *(const float2*)(in + (size_t)row * E_SZ + tid * 2);
  float s = v.x + v.y;
#pragma unroll
  for (int o = 32; o; o >>= 1) s += __shfl_xor(s, o);
  __shared__ float w1[4], w2[4];
  if ((tid & 63) == 0) w1[tid >> 6] = s;
  __syncthreads();
  const float mean = (w1[0] + w1[1] + w1[2] + w1[3]) * (1.f / 512.f);
  const float d0 = v.x - mean, d1 = v.y - mean;
  float q = d0 * d0 + d1 * d1;
#pragma unroll
  for (int o = 32; o; o >>= 1) q += __shfl_xor(q, o);
  if ((tid & 63) == 0) w2[tid >> 6] = q;
  __syncthreads();
  const float var = (w2[0] + w2[1] + w2[2] + w2[3]) * (1.f / 512.f);
  const float inv = rsqrtf(var + 1e-5f);
  const float2 sv = *(const float2*)(sc + tid * 2);
  const float2 bv = *(const float2*)(bi + tid * 2);
  __hip_bfloat162 ov;
  ov.x = __float2bfloat16(d0 * inv * sv.x + bv.x);
  ov.y = __float2bfloat16(d1 * inv * sv.y + bv.y);
  *(__hip_bfloat162*)(out + (size_t)row * E_SZ + tid * 2) = ov;
}

// ---------------------------------------------------------------------------
// Weight prep: W_emb [V][512] f32 -> [V_PAD][512] bf16 (zero-padded rows)
// ---------------------------------------------------------------------------
__global__ __launch_bounds__(256) void convert_wemb(
    const float* __restrict__ W, __hip_bfloat16* __restrict__ Wb) {
  const int tid = blockIdx.x * 256 + threadIdx.x;
  const int row = tid >> 6;
  const int c = (tid & 63) * 8;
  union { __hip_bfloat16 h[8]; int4 v; } u;
  if (row < V_SZ) {
    const float* p = W + (size_t)row * E_SZ + c;
#pragma unroll
    for (int j = 0; j < 8; ++j) u.h[j] = __float2bfloat16(p[j]);
  } else {
#pragma unroll
    for (int j = 0; j < 8; ++j) u.h[j] = __float2bfloat16(0.f);
  }
  *(int4*)(Wb + (size_t)row * E_SZ + c) = u.v;
}

// ---------------------------------------------------------------------------
// Batched transpose+convert: in [L][K][N] f32 -> out [L][Npad][Kpad] bf16
// grid (Npad/32, Kpad/32, L), 256 threads.
// ---------------------------------------------------------------------------
__global__ __launch_bounds__(256) void transp_convert(
    const float* __restrict__ in, __hip_bfloat16* __restrict__ out,
    int K, int N, int Kpad, int Npad) {
  __shared__ float tile[32][33];
  const int l = blockIdx.z;
  in  += (size_t)l * K * N;
  out += (size_t)l * Npad * Kpad;
  const int tx = threadIdx.x & 31, ty = threadIdx.x >> 5;
  const int n0 = blockIdx.x * 32, k0 = blockIdx.y * 32;
#pragma unroll
  for (int i = 0; i < 4; ++i) {
    const int k = k0 + ty + i * 8, n = n0 + tx;
    tile[ty + i * 8][tx] = (k < K && n < N) ? in[(size_t)k * N + n] : 0.f;
  }
  __syncthreads();
#pragma unroll
  for (int i = 0; i < 4; ++i) {
    const int n = n0 + ty + i * 8, kk = k0 + tx;
    out[(size_t)n * Kpad + kk] = __float2bfloat16(tile[tx][ty + i * 8]);
  }
}

// ---------------------------------------------------------------------------
// gate/up interleaved prep: out [L][2816][512] bf16 where output row n:
// role=(n>>4)&1 (0=gate,1=up), c=((n>>5)<<4)+(n&15); out[n][k]=src[k][c].
// One wave per output row; 8 k per thread. grid (704, L), 256 thr.
// ---------------------------------------------------------------------------
__global__ __launch_bounds__(256) void gu_prep(
    const float* __restrict__ gate, const float* __restrict__ up,
    __hip_bfloat16* __restrict__ outw) {
  const int l = blockIdx.y;
  const int tid = blockIdx.x * 256 + threadIdx.x;
  const int n = tid >> 6;            // 0..2815
  const int k0 = (tid & 63) * 8;
  const int role = (n >> 4) & 1;
  const int c = ((n >> 5) << 4) | (n & 15);
  union { __hip_bfloat16 h[8]; int4 v; } u;
  if (c < HID_SZ) {
    const float* src = (role ? up : gate) + (size_t)l * E_SZ * HID_SZ + c;
#pragma unroll
    for (int j = 0; j < 8; ++j)
      u.h[j] = __float2bfloat16(src[(size_t)(k0 + j) * HID_SZ]);
  } else {
#pragma unroll
    for (int j = 0; j < 8; ++j) u.h[j] = __float2bfloat16(0.f);
  }
  *(int4*)(outw + ((size_t)l * 2816 + n) * E_SZ + k0) = u.v;
}

// ---------------------------------------------------------------------------
// bf16 MFMA GEMM (m97 structure): C = A[M,K](bf16) @ B^T, B [Npad][K] bf16.
// EPI: 0 = f32 store, 1 = bf16 store, 2 = f32 + residual, 3 = SwiGLU->bf16
// (gate/up interleaved in 16-col tiles; output cols N/2, stride HID_PAD).
// ---------------------------------------------------------------------------
template <int EPI, bool BOUND>
__global__ __launch_bounds__(256) void mfma_gemm(
    const __hip_bfloat16* __restrict__ A, const __hip_bfloat16* __restrict__ B,
    void* __restrict__ Cv, const float* __restrict__ R, int N, int K) {
  __shared__ char lds[16384];
  const int tid = threadIdx.x;
  const int lane = tid & 63, w = tid >> 6;
  const int wr = w >> 1, wc = w & 1;
  const int m0 = blockIdx.y * 128, n0 = blockIdx.x * 128;
  const size_t SA = (size_t)K * 2;

  f32x4 acc[4][4] = {};
  char* As = lds;
  char* Bs = lds + 8192;
  const char* Ab = (const char*)A + (size_t)m0 * SA;
  const char* Bb = (const char*)B + (size_t)n0 * SA;

  const int r = lane >> 2, cb = (lane & 3) * 16;
  for (int k0 = 0; k0 < K; k0 += 32) {
#pragma unroll
    for (int cc2 = 0; cc2 < 2; ++cc2) {
      const int c = w * 2 + cc2;
      const char* ga = Ab + (size_t)(c * 16 + r) * SA + k0 * 2 + cb;
      __builtin_amdgcn_global_load_lds(
          (const __attribute__((address_space(1))) unsigned int*)ga,
          (__attribute__((address_space(3))) unsigned int*)(As + c * 1024),
          16, 0, 0);
      const char* gb = Bb + (size_t)(c * 16 + r) * SA + k0 * 2 + cb;
      __builtin_amdgcn_global_load_lds(
          (const __attribute__((address_space(1))) unsigned int*)gb,
          (__attribute__((address_space(3))) unsigned int*)(Bs + c * 1024),
          16, 0, 0);
    }
    __syncthreads();
    bf16x8 a[4], b[4];
    const int kb = (lane >> 4) * 16;
#pragma unroll
    for (int i = 0; i < 4; ++i) {
      a[i] = *(const bf16x8*)(As + (wr * 64 + i * 16 + (lane & 15)) * 64 + kb);
      b[i] = *(const bf16x8*)(Bs + (wc * 64 + i * 16 + (lane & 15)) * 64 + kb);
    }
#pragma unroll
    for (int i = 0; i < 4; ++i)
#pragma unroll
      for (int j = 0; j < 4; ++j)
        acc[i][j] = __builtin_amdgcn_mfma_f32_16x16x32_bf16(a[i], b[j], acc[i][j], 0, 0, 0);
    __syncthreads();
  }

  // C/D layout: col = lane&15, row = (lane>>4)*4 + reg
  const int cr = (lane >> 4) * 4, ccol = lane & 15;
  if (EPI == 3) {
    __hip_bfloat16* G = (__hip_bfloat16*)Cv;
#pragma unroll
    for (int i = 0; i < 4; ++i) {
#pragma unroll
      for (int p = 0; p < 2; ++p) {
        const int cg = (n0 >> 1) + wc * 32 + p * 16 + ccol;
#pragma unroll
        for (int rr = 0; rr < 4; ++rr) {
          const int m = m0 + wr * 64 + i * 16 + cr + rr;
          const float gv = acc[i][2 * p][rr];
          const float uv = acc[i][2 * p + 1][rr];
          const float val = gv / (1.f + __expf(-gv)) * uv;
          G[(size_t)m * HID_PAD + cg] = __float2bfloat16(val);
        }
      }
    }
    return;
  }
#pragma unroll
  for (int i = 0; i < 4; ++i) {
#pragma unroll
    for (int j = 0; j < 4; ++j) {
      const int n = n0 + wc * 64 + j * 16 + ccol;
      if (BOUND && n >= N) continue;
#pragma unroll
      for (int rr = 0; rr < 4; ++rr) {
        const int m = m0 + wr * 64 + i * 16 + cr + rr;
        float v = acc[i][j][rr];
        if (EPI == 2) v += R[(size_t)m * N + n];
        if (EPI == 1) ((__hip_bfloat16*)Cv)[(size_t)m * N + n] = __float2bfloat16(v);
        else ((float*)Cv)[(size_t)m * N + n] = v;
      }
    }
  }
}

// ---------------------------------------------------------------------------
// Flash attention with 32x32x16 MFMA, swapped operands (unchanged from R3).
// ---------------------------------------------------------------------------
__global__ __launch_bounds__(128) void attn_mfma_kernel(
    const __hip_bfloat16* __restrict__ qkv, __hip_bfloat16* __restrict__ o) {
  const int bid = blockIdx.x;
  const int qb = bid & 15;
  const int h = (bid >> 4) & 7;
  const int b = bid >> 7;
  const int tid = threadIdx.x;
  const int w = tid >> 6, lane = tid & 63;
  const int l31 = lane & 31, hi = lane >> 5;
  const int q0w = qb * 64 + 32 * w;
  const float slope = exp2f(-(float)(h + 1));
  const int rowstride = 3 * E_SZ;

  __shared__ char lds[16384];
  char* Kl = lds;
  char* Vl = lds + 8192;

  bf16x8 qf[4];
  {
    const __hip_bfloat16* qrow = qkv + (size_t)(b * T_SZ + q0w + l31) * rowstride + h * HD_SZ;
#pragma unroll
    for (int dblk = 0; dblk < 4; ++dblk)
      qf[dblk] = *(const bf16x8*)(qrow + dblk * 16 + hi * 8);
  }

  f32x16 oacc[2] = {};
  float m = -INFINITY, lsum = 0.f;

  for (int c = 0; c <= qb; ++c) {
    const int j0c = c * 64;
    {  // stage K [64 kv][64 d] bf16, swizzled byte ^= ((kv&7)<<4)
      const int j = tid >> 1, half = tid & 1;
      const __hip_bfloat16* src = qkv + (size_t)(b * T_SZ + j0c + j) * rowstride + E_SZ + h * HD_SZ + half * 32;
#pragma unroll
      for (int u2 = 0; u2 < 4; ++u2) {
        int4 v = *(const int4*)(src + u2 * 8);
        const int d0 = half * 32 + u2 * 8;
        *(int4*)(Kl + j * 128 + ((2 * d0) ^ ((j & 7) << 4))) = v;
      }
    }
    {  // stage VT [64 d][64 j] bf16 (transposed), swizzled byte ^= ((d&7)<<4)
      const int jp = tid >> 2, quarter = tid & 3;
      const int j0 = jp * 2, d0 = quarter * 16;
      const __hip_bfloat16* s0 = qkv + (size_t)(b * T_SZ + j0c + j0) * rowstride + 2 * E_SZ + h * HD_SZ + d0;
      const __hip_bfloat16* s1 = s0 + rowstride;
      union { int4 v[2]; unsigned short us[16]; } aa, bb;
      aa.v[0] = *(const int4*)(s0);  aa.v[1] = *(const int4*)(s0 + 8);
      bb.v[0] = *(const int4*)(s1);  bb.v[1] = *(const int4*)(s1 + 8);
#pragma unroll
      for (int e = 0; e < 16; ++e) {
        const int d = d0 + e;
        const unsigned wv = (unsigned)aa.us[e] | ((unsigned)bb.us[e] << 16);
        *(unsigned*)(Vl + d * 128 + ((2 * j0) ^ ((d & 7) << 4))) = wv;
      }
    }
    __syncthreads();
#pragma unroll
    for (int s = 0; s < 2; ++s) {
      const int j0 = j0c + 32 * s;
      if (j0 <= q0w + 31) {
        f32x16 sacc = {};
        const int jrow = 32 * s + l31;
#pragma unroll
        for (int dblk = 0; dblk < 4; ++dblk) {
          bf16x8 kf = *(const bf16x8*)(Kl + jrow * 128 + ((dblk * 32 + hi * 16) ^ ((jrow & 7) << 4)));
          sacc = __builtin_amdgcn_mfma_f32_32x32x16_bf16(kf, qf[dblk], sacc, 0, 0, 0);
        }
        const int qg = q0w + l31;
        float p[16];
        float tmax = -1e30f;
#pragma unroll
        for (int r = 0; r < 16; ++r) {
          const int jg = j0 + (r & 3) + 8 * (r >> 2) + 4 * hi;
          const float sv = (jg > qg) ? -1e9f : (sacc[r] * 0.125f + slope * (float)(qg - jg));
          p[r] = sv;
          tmax = fmaxf(tmax, sv);
        }
        tmax = fmaxf(tmax, __shfl_xor(tmax, 32));
        const float mnew = fmaxf(m, tmax);
        const float corr = __expf(m - mnew);
        float tsum = 0.f;
#pragma unroll
        for (int r = 0; r < 16; ++r) {
          p[r] = __expf(p[r] - mnew);
          tsum += p[r];
        }
        tsum += __shfl_xor(tsum, 32);
        lsum = lsum * corr + tsum;
        m = mnew;
#pragma unroll
        for (int dt = 0; dt < 2; ++dt)
#pragma unroll
          for (int r = 0; r < 16; ++r) oacc[dt][r] *= corr;
        unsigned wds[8];
#pragma unroll
        for (int k = 0; k < 8; ++k) {
          union { __hip_bfloat16 hh[2]; unsigned u; } pk_;
          pk_.hh[0] = __float2bfloat16(p[2 * k]);
          pk_.hh[1] = __float2bfloat16(p[2 * k + 1]);
          wds[k] = pk_.u;
        }
        bf16x8 pfrag[2];
#pragma unroll
        for (int jb = 0; jb < 2; ++jb) {
          const unsigned w0 = wds[4 * jb + 0], w1 = wds[4 * jb + 1];
          const unsigned w2 = wds[4 * jb + 2], w3 = wds[4 * jb + 3];
          const unsigned x2 = (unsigned)__shfl_xor((int)w2, 32);
          const unsigned x3 = (unsigned)__shfl_xor((int)w3, 32);
          const unsigned x0 = (unsigned)__shfl_xor((int)w0, 32);
          const unsigned x1 = (unsigned)__shfl_xor((int)w1, 32);
          union { unsigned u[4]; bf16x8 v; } pf;
          pf.u[0] = hi ? x2 : w0;
          pf.u[1] = hi ? x3 : w1;
          pf.u[2] = hi ? w2 : x0;
          pf.u[3] = hi ? w3 : x1;
          pfrag[jb] = pf.v;
        }
#pragma unroll
        for (int dt = 0; dt < 2; ++dt) {
          const int row = dt * 32 + l31;
#pragma unroll
          for (int jb = 0; jb < 2; ++jb) {
            bf16x8 vt = *(const bf16x8*)(Vl + row * 128 + ((s * 64 + jb * 32 + hi * 16) ^ ((row & 7) << 4)));
            oacc[dt] = __builtin_amdgcn_mfma_f32_32x32x16_bf16(vt, pfrag[jb], oacc[dt], 0, 0, 0);
          }
        }
      }
    }
    __syncthreads();
  }
  const float inv = 1.f / lsum;
  __hip_bfloat16* orow = o + (size_t)(b * T_SZ + q0w + l31) * E_SZ + h * HD_SZ;
#pragma unroll
  for (int dt = 0; dt < 2; ++dt) {
#pragma unroll
    for (int g = 0; g < 4; ++g) {
      union { __hip_bfloat16 hh[4]; short4 v; } ov;
#pragma unroll
      for (int e = 0; e < 4; ++e)
        ov.hh[e] = __float2bfloat16(oacc[dt][4 * g + e] * inv);
      *(short4*)(orow + dt * 32 + 4 * hi + 8 * g) = ov.v;
    }
  }
}

// ---------------------------------------------------------------------------
extern "C" void kernel_launch(void* const* d_in, const int* in_sizes, int n_in,
                              void* d_out, int out_size, void* d_ws, size_t ws_size,
                              hipStream_t stream) {
  const int* idx      = (const int*)d_in[0];
  const float* W_emb  = (const float*)d_in[1];
  const float* pos    = (const float*)d_in[2];
  const float* ln1_s  = (const float*)d_in[3];
  const float* ln1_b  = (const float*)d_in[4];
  const float* qkv_w  = (const float*)d_in[5];
  const float* proj_w = (const float*)d_in[6];
  const float* ln2_s  = (const float*)d_in[7];
  const float* ln2_b  = (const float*)d_in[8];
  const float* gate_w = (const float*)d_in[9];
  const float* up_w   = (const float*)d_in[10];
  const float* down_w = (const float*)d_in[11];
  const float* lnf_s  = (const float*)d_in[12];
  const float* lnf_b  = (const float*)d_in[13];
  float* out = (float*)d_out;

  char* p = (char*)d_ws;
  auto alloc = [&](size_t bytes) { char* q = p; p += (bytes + 255) & ~255ULL; return q; };
  float* x    = (float*)alloc((size_t)ROWS * E_SZ * 4);
  __hip_bfloat16* qkv_bf = (__hip_bfloat16*)alloc((size_t)ROWS * 3 * E_SZ * 2);
  __hip_bfloat16* h_bf  = (__hip_bfloat16*)alloc((size_t)ROWS * E_SZ * 2);
  __hip_bfloat16* o_bf  = (__hip_bfloat16*)alloc((size_t)ROWS * E_SZ * 2);
  __hip_bfloat16* g_bf  = (__hip_bfloat16*)alloc((size_t)ROWS * HID_PAD * 2);
  __hip_bfloat16* Wb    = (__hip_bfloat16*)alloc((size_t)V_PAD * E_SZ * 2);
  __hip_bfloat16* qkvwb = (__hip_bfloat16*)alloc((size_t)L_N * 3 * E_SZ * E_SZ * 2);
  __hip_bfloat16* projwb= (__hip_bfloat16*)alloc((size_t)L_N * E_SZ * E_SZ * 2);
  __hip_bfloat16* guwb  = (__hip_bfloat16*)alloc((size_t)L_N * 2816 * E_SZ * 2);
  __hip_bfloat16* downwb= (__hip_bfloat16*)alloc((size_t)L_N * E_SZ * HID_PAD * 2);

  // ---- weight prep: 5 batched launches ----
  convert_wemb<<<(V_PAD * E_SZ / 8 + 255) / 256, 256, 0, stream>>>(W_emb, Wb);
  transp_convert<<<dim3(3 * E_SZ / 32, E_SZ / 32, L_N), 256, 0, stream>>>(
      qkv_w, qkvwb, E_SZ, 3 * E_SZ, E_SZ, 3 * E_SZ);
  transp_convert<<<dim3(E_SZ / 32, E_SZ / 32, L_N), 256, 0, stream>>>(
      proj_w, projwb, E_SZ, E_SZ, E_SZ, E_SZ);
  gu_prep<<<dim3(704, L_N), 256, 0, stream>>>(gate_w, up_w, guwb);
  transp_convert<<<dim3(E_SZ / 32, HID_PAD / 32, L_N), 256, 0, stream>>>(
      down_w, downwb, HID_SZ, E_SZ, HID_PAD, E_SZ);

  embed_kernel<<<ROWS, 128, 0, stream>>>(idx, W_emb, pos, x);

  for (int l = 0; l < L_N; ++l) {
    ln_kernel<<<ROWS, 256, 0, stream>>>(x, h_bf, ln1_s + l * E_SZ, ln1_b + l * E_SZ);
    mfma_gemm<1, false><<<dim3(12, 16), 256, 0, stream>>>(
        h_bf, qkvwb + (size_t)l * 3 * E_SZ * E_SZ, qkv_bf, nullptr, 3 * E_SZ, E_SZ);
    attn_mfma_kernel<<<B_SZ * H_N * (T_SZ / 64), 128, 0, stream>>>(qkv_bf, o_bf);
    mfma_gemm<2, false><<<dim3(4, 16), 256, 0, stream>>>(
        o_bf, projwb + (size_t)l * E_SZ * E_SZ, x, x, E_SZ, E_SZ);
    ln_kernel<<<ROWS, 256, 0, stream>>>(x, h_bf, ln2_s + l * E_SZ, ln2_b + l * E_SZ);
    mfma_gemm<3, false><<<dim3(22, 16), 256, 0, stream>>>(
        h_bf, guwb + (size_t)l * 2816 * E_SZ, g_bf, nullptr, 2816, E_SZ);
    mfma_gemm<2, false><<<dim3(4, 16), 256, 0, stream>>>(
        g_bf, downwb + (size_t)l * E_SZ * HID_PAD, x, x, E_SZ, HID_PAD);
  }

  ln_kernel<<<ROWS, 256, 0, stream>>>(x, h_bf, lnf_s, lnf_b);
  mfma_gemm<0, true><<<dim3(V_PAD / 128, 16), 256, 0, stream>>>(
      h_bf, Wb, out, nullptr, V_SZ, E_SZ);
}

// Round 6
// 1346.439 us; speedup vs baseline: 10.6784x; 1.0025x over previous
//
#include <hip/hip_runtime.h>
#include <hip/hip_bf16.h>
#include <math.h>

#define V_SZ 50257
#define V_PAD 50304
#define E_SZ 512
#define H_N 8
#define L_N 8
#define HID_SZ 1365
#define HID_PAD 1408
#define T_SZ 1024
#define B_SZ 2
#define HD_SZ 64
#define ROWS (B_SZ * T_SZ)   // 2048

typedef short bf16x8 __attribute__((ext_vector_type(8)));
typedef float f32x4 __attribute__((ext_vector_type(4)));
typedef float f32x16 __attribute__((ext_vector_type(16)));

// ---------------------------------------------------------------------------
// Embedding: x[b,t,:] = W_emb[idx[b,t],:] + pos_emb[t,:]   (f32 out)
// ---------------------------------------------------------------------------
__global__ __launch_bounds__(128) void embed_kernel(
    const int* __restrict__ idx, const float* __restrict__ W,
    const float* __restrict__ P, float* __restrict__ x) {
  const int bt = blockIdx.x;
  const int t = bt & (T_SZ - 1);
  const int id = idx[bt];
  const int e = threadIdx.x * 4;
  float4 w = *(const float4*)(W + (size_t)id * E_SZ + e);
  float4 p = *(const float4*)(P + (size_t)t * E_SZ + e);
  float4 r;
  r.x = w.x + p.x; r.y = w.y + p.y; r.z = w.z + p.z; r.w = w.w + p.w;
  *(float4*)(x + (size_t)bt * E_SZ + e) = r;
}

// ---------------------------------------------------------------------------
// LayerNorm over E=512, f32 in -> bf16 out. One block (256 thr) per row.
// ---------------------------------------------------------------------------
__global__ __launch_bounds__(256) void ln_kernel(
    const float* __restrict__ in, __hip_bfloat16* __restrict__ out,
    const float* __restrict__ sc, const float* __restrict__ bi) {
  const int row = blockIdx.x;
  const int tid = threadIdx.x;
  const float2 v = *(const float2*)(in + (size_t)row * E_SZ + tid * 2);
  float s = v.x + v.y;
#pragma unroll
  for (int o = 32; o; o >>= 1) s += __shfl_xor(s, o);
  __shared__ float w1[4], w2[4];
  if ((tid & 63) == 0) w1[tid >> 6] = s;
  __syncthreads();
  const float mean = (w1[0] + w1[1] + w1[2] + w1[3]) * (1.f / 512.f);
  const float d0 = v.x - mean, d1 = v.y - mean;
  float q = d0 * d0 + d1 * d1;
#pragma unroll
  for (int o = 32; o; o >>= 1) q += __shfl_xor(q, o);
  if ((tid & 63) == 0) w2[tid >> 6] = q;
  __syncthreads();
  const float var = (w2[0] + w2[1] + w2[2] + w2[3]) * (1.f / 512.f);
  const float inv = rsqrtf(var + 1e-5f);
  const float2 sv = *(const float2*)(sc + tid * 2);
  const float2 bv = *(const float2*)(bi + tid * 2);
  __hip_bfloat162 ov;
  ov.x = __float2bfloat16(d0 * inv * sv.x + bv.x);
  ov.y = __float2bfloat16(d1 * inv * sv.y + bv.y);
  *(__hip_bfloat162*)(out + (size_t)row * E_SZ + tid * 2) = ov;
}

// ---------------------------------------------------------------------------
// Weight prep: W_emb [V][512] f32 -> [V_PAD][512] bf16 (zero-padded rows)
// ---------------------------------------------------------------------------
__global__ __launch_bounds__(256) void convert_wemb(
    const float* __restrict__ W, __hip_bfloat16* __restrict__ Wb) {
  const int tid = blockIdx.x * 256 + threadIdx.x;
  const int row = tid >> 6;
  const int c = (tid & 63) * 8;
  union { __hip_bfloat16 h[8]; int4 v; } u;
  if (row < V_SZ) {
    const float* p = W + (size_t)row * E_SZ + c;
#pragma unroll
    for (int j = 0; j < 8; ++j) u.h[j] = __float2bfloat16(p[j]);
  } else {
#pragma unroll
    for (int j = 0; j < 8; ++j) u.h[j] = __float2bfloat16(0.f);
  }
  *(int4*)(Wb + (size_t)row * E_SZ + c) = u.v;
}

// ---------------------------------------------------------------------------
// Batched transpose+convert: in [L][K][N] f32 -> out [L][Npad][Kpad] bf16
// grid (Npad/32, Kpad/32, L), 256 threads.
// ---------------------------------------------------------------------------
__global__ __launch_bounds__(256) void transp_convert(
    const float* __restrict__ in, __hip_bfloat16* __restrict__ out,
    int K, int N, int Kpad, int Npad) {
  __shared__ float tile[32][33];
  const int l = blockIdx.z;
  in  += (size_t)l * K * N;
  out += (size_t)l * Npad * Kpad;
  const int tx = threadIdx.x & 31, ty = threadIdx.x >> 5;
  const int n0 = blockIdx.x * 32, k0 = blockIdx.y * 32;
#pragma unroll
  for (int i = 0; i < 4; ++i) {
    const int k = k0 + ty + i * 8, n = n0 + tx;
    tile[ty + i * 8][tx] = (k < K && n < N) ? in[(size_t)k * N + n] : 0.f;
  }
  __syncthreads();
#pragma unroll
  for (int i = 0; i < 4; ++i) {
    const int n = n0 + ty + i * 8, kk = k0 + tx;
    out[(size_t)n * Kpad + kk] = __float2bfloat16(tile[tx][ty + i * 8]);
  }
}

// ---------------------------------------------------------------------------
// gate/up interleaved prep, COALESCED (LDS-tiled transpose).
// out [L][2816][512] bf16; output row for col c, role r: n=((c>>4)<<5)|(r<<4)|(c&15).
// grid (44, 16, L), 256 thr.
// ---------------------------------------------------------------------------
__global__ __launch_bounds__(256) void gu_prep(
    const float* __restrict__ gate, const float* __restrict__ up,
    __hip_bfloat16* __restrict__ outw) {
  __shared__ float tile[32][33];
  const int l = blockIdx.z;
  const int c0 = blockIdx.x * 32, k0 = blockIdx.y * 32;
  const int tx = threadIdx.x & 31, ty = threadIdx.x >> 5;
#pragma unroll
  for (int role = 0; role < 2; ++role) {
    const float* src = (role ? up : gate) + (size_t)l * E_SZ * HID_SZ;
#pragma unroll
    for (int i = 0; i < 4; ++i) {
      const int k = k0 + ty + i * 8, c = c0 + tx;
      tile[ty + i * 8][tx] = (c < HID_SZ) ? src[(size_t)k * HID_SZ + c] : 0.f;
    }
    __syncthreads();
#pragma unroll
    for (int i = 0; i < 4; ++i) {
      const int c = c0 + ty + i * 8, kk = k0 + tx;
      const int n = ((c >> 4) << 5) | (role << 4) | (c & 15);
      outw[((size_t)l * 2816 + n) * E_SZ + kk] = __float2bfloat16(tile[tx][ty + i * 8]);
    }
    __syncthreads();
  }
}

// ---------------------------------------------------------------------------
// bf16 MFMA GEMM (m97 structure): C = A[M,K](bf16) @ B^T, B [Npad][K] bf16.
// EPI: 0 = f32 store, 1 = bf16 store, 2 = f32 + residual, 3 = SwiGLU->bf16
// ---------------------------------------------------------------------------
template <int EPI, bool BOUND>
__global__ __launch_bounds__(256) void mfma_gemm(
    const __hip_bfloat16* __restrict__ A, const __hip_bfloat16* __restrict__ B,
    void* __restrict__ Cv, const float* __restrict__ R, int N, int K) {
  __shared__ char lds[16384];
  const int tid = threadIdx.x;
  const int lane = tid & 63, w = tid >> 6;
  const int wr = w >> 1, wc = w & 1;
  const int m0 = blockIdx.y * 128, n0 = blockIdx.x * 128;
  const size_t SA = (size_t)K * 2;

  f32x4 acc[4][4] = {};
  char* As = lds;
  char* Bs = lds + 8192;
  const char* Ab = (const char*)A + (size_t)m0 * SA;
  const char* Bb = (const char*)B + (size_t)n0 * SA;

  const int r = lane >> 2, cb = (lane & 3) * 16;
  for (int k0 = 0; k0 < K; k0 += 32) {
#pragma unroll
    for (int cc2 = 0; cc2 < 2; ++cc2) {
      const int c = w * 2 + cc2;
      const char* ga = Ab + (size_t)(c * 16 + r) * SA + k0 * 2 + cb;
      __builtin_amdgcn_global_load_lds(
          (const __attribute__((address_space(1))) unsigned int*)ga,
          (__attribute__((address_space(3))) unsigned int*)(As + c * 1024),
          16, 0, 0);
      const char* gb = Bb + (size_t)(c * 16 + r) * SA + k0 * 2 + cb;
      __builtin_amdgcn_global_load_lds(
          (const __attribute__((address_space(1))) unsigned int*)gb,
          (__attribute__((address_space(3))) unsigned int*)(Bs + c * 1024),
          16, 0, 0);
    }
    __syncthreads();
    bf16x8 a[4], b[4];
    const int kb = (lane >> 4) * 16;
#pragma unroll
    for (int i = 0; i < 4; ++i) {
      a[i] = *(const bf16x8*)(As + (wr * 64 + i * 16 + (lane & 15)) * 64 + kb);
      b[i] = *(const bf16x8*)(Bs + (wc * 64 + i * 16 + (lane & 15)) * 64 + kb);
    }
#pragma unroll
    for (int i = 0; i < 4; ++i)
#pragma unroll
      for (int j = 0; j < 4; ++j)
        acc[i][j] = __builtin_amdgcn_mfma_f32_16x16x32_bf16(a[i], b[j], acc[i][j], 0, 0, 0);
    __syncthreads();
  }

  const int cr = (lane >> 4) * 4, ccol = lane & 15;
  if (EPI == 3) {
    __hip_bfloat16* G = (__hip_bfloat16*)Cv;
#pragma unroll
    for (int i = 0; i < 4; ++i) {
#pragma unroll
      for (int p = 0; p < 2; ++p) {
        const int cg = (n0 >> 1) + wc * 32 + p * 16 + ccol;
#pragma unroll
        for (int rr = 0; rr < 4; ++rr) {
          const int m = m0 + wr * 64 + i * 16 + cr + rr;
          const float gv = acc[i][2 * p][rr];
          const float uv = acc[i][2 * p + 1][rr];
          const float val = gv / (1.f + __expf(-gv)) * uv;
          G[(size_t)m * HID_PAD + cg] = __float2bfloat16(val);
        }
      }
    }
    return;
  }
#pragma unroll
  for (int i = 0; i < 4; ++i) {
#pragma unroll
    for (int j = 0; j < 4; ++j) {
      const int n = n0 + wc * 64 + j * 16 + ccol;
      if (BOUND && n >= N) continue;
#pragma unroll
      for (int rr = 0; rr < 4; ++rr) {
        const int m = m0 + wr * 64 + i * 16 + cr + rr;
        float v = acc[i][j][rr];
        if (EPI == 2) v += R[(size_t)m * N + n];
        if (EPI == 1) ((__hip_bfloat16*)Cv)[(size_t)m * N + n] = __float2bfloat16(v);
        else ((float*)Cv)[(size_t)m * N + n] = v;
      }
    }
  }
}

// ---------------------------------------------------------------------------
// Flash attention, 32x32x16 MFMA, swapped operands, DOUBLE-BUFFERED staging:
// issue chunk c+1 global loads -> regs before compute(c); ds_write after.
// One barrier per chunk.
// ---------------------------------------------------------------------------
__global__ __launch_bounds__(128) void attn_mfma_kernel(
    const __hip_bfloat16* __restrict__ qkv, __hip_bfloat16* __restrict__ o) {
  const int bid = blockIdx.x;
  const int qb = bid & 15;
  const int h = (bid >> 4) & 7;
  const int b = bid >> 7;
  const int tid = threadIdx.x;
  const int w = tid >> 6, lane = tid & 63;
  const int l31 = lane & 31, hi = lane >> 5;
  const int q0w = qb * 64 + 32 * w;
  const float slope = exp2f(-(float)(h + 1));
  const int rowstride = 3 * E_SZ;

  __shared__ char lds[32768];   // 2 buffers x (K 8KB | V 8KB)

  bf16x8 qf[4];
  {
    const __hip_bfloat16* qrow = qkv + (size_t)(b * T_SZ + q0w + l31) * rowstride + h * HD_SZ;
#pragma unroll
    for (int dblk = 0; dblk < 4; ++dblk)
      qf[dblk] = *(const bf16x8*)(qrow + dblk * 16 + hi * 8);
  }

  f32x16 oacc[2] = {};
  float m = -INFINITY, lsum = 0.f;

  // staging registers + per-thread staging geometry
  int4 kreg[4], va[2], vb[2];
  const int jK = tid >> 1, halfK = tid & 1;
  const int jpV = tid >> 2, qtrV = tid & 3;
  const int d0V = qtrV * 16;

  auto ISSUE = [&](int c) {
    const __hip_bfloat16* srcK = qkv + (size_t)(b * T_SZ + c * 64 + jK) * rowstride + E_SZ + h * HD_SZ + halfK * 32;
    kreg[0] = ((const int4*)srcK)[0]; kreg[1] = ((const int4*)srcK)[1];
    kreg[2] = ((const int4*)srcK)[2]; kreg[3] = ((const int4*)srcK)[3];
    const __hip_bfloat16* srcV = qkv + (size_t)(b * T_SZ + c * 64 + jpV * 2) * rowstride + 2 * E_SZ + h * HD_SZ + d0V;
    va[0] = ((const int4*)srcV)[0]; va[1] = ((const int4*)srcV)[1];
    vb[0] = ((const int4*)(srcV + rowstride))[0]; vb[1] = ((const int4*)(srcV + rowstride))[1];
  };
  auto WRITE = [&](int bufidx) {
    char* Kb = lds + bufidx * 16384;
    char* Vb = Kb + 8192;
#pragma unroll
    for (int u2 = 0; u2 < 4; ++u2) {
      const int d0 = halfK * 32 + u2 * 8;
      *(int4*)(Kb + jK * 128 + ((2 * d0) ^ ((jK & 7) << 4))) = kreg[u2];
    }
    union { int4 v[2]; unsigned short us[16]; } ua, ub;
    ua.v[0] = va[0]; ua.v[1] = va[1]; ub.v[0] = vb[0]; ub.v[1] = vb[1];
    const int j0 = jpV * 2;
#pragma unroll
    for (int e = 0; e < 16; ++e) {
      const int d = d0V + e;
      const unsigned wv = (unsigned)ua.us[e] | ((unsigned)ub.us[e] << 16);
      *(unsigned*)(Vb + d * 128 + ((2 * j0) ^ ((d & 7) << 4))) = wv;
    }
  };

  ISSUE(0);
  WRITE(0);
  for (int c = 0; c <= qb; ++c) {
    const int buf = c & 1;
    if (c < qb) ISSUE(c + 1);
    __syncthreads();
    const char* Kl = lds + buf * 16384;
    const char* Vl = Kl + 8192;
    const int j0c = c * 64;
#pragma unroll
    for (int s = 0; s < 2; ++s) {
      const int j0 = j0c + 32 * s;
      if (j0 <= q0w + 31) {
        f32x16 sacc = {};
        const int jrow = 32 * s + l31;
        __builtin_amdgcn_s_setprio(1);
#pragma unroll
        for (int dblk = 0; dblk < 4; ++dblk) {
          bf16x8 kf = *(const bf16x8*)(Kl + jrow * 128 + ((dblk * 32 + hi * 16) ^ ((jrow & 7) << 4)));
          sacc = __builtin_amdgcn_mfma_f32_32x32x16_bf16(kf, qf[dblk], sacc, 0, 0, 0);
        }
        __builtin_amdgcn_s_setprio(0);
        const int qg = q0w + l31;
        float p[16];
        float tmax = -1e30f;
#pragma unroll
        for (int r = 0; r < 16; ++r) {
          const int jg = j0 + (r & 3) + 8 * (r >> 2) + 4 * hi;
          const float sv = (jg > qg) ? -1e9f : (sacc[r] * 0.125f + slope * (float)(qg - jg));
          p[r] = sv;
          tmax = fmaxf(tmax, sv);
        }
        tmax = fmaxf(tmax, __shfl_xor(tmax, 32));
        const float mnew = fmaxf(m, tmax);
        const float corr = __expf(m - mnew);
        float tsum = 0.f;
#pragma unroll
        for (int r = 0; r < 16; ++r) {
          p[r] = __expf(p[r] - mnew);
          tsum += p[r];
        }
        tsum += __shfl_xor(tsum, 32);
        lsum = lsum * corr + tsum;
        m = mnew;
#pragma unroll
        for (int dt = 0; dt < 2; ++dt)
#pragma unroll
          for (int r = 0; r < 16; ++r) oacc[dt][r] *= corr;
        unsigned wds[8];
#pragma unroll
        for (int k = 0; k < 8; ++k) {
          union { __hip_bfloat16 hh[2]; unsigned u; } pk_;
          pk_.hh[0] = __float2bfloat16(p[2 * k]);
          pk_.hh[1] = __float2bfloat16(p[2 * k + 1]);
          wds[k] = pk_.u;
        }
        bf16x8 pfrag[2];
#pragma unroll
        for (int jb = 0; jb < 2; ++jb) {
          const unsigned w0 = wds[4 * jb + 0], w1 = wds[4 * jb + 1];
          const unsigned w2 = wds[4 * jb + 2], w3 = wds[4 * jb + 3];
          const unsigned x2 = (unsigned)__shfl_xor((int)w2, 32);
          const unsigned x3 = (unsigned)__shfl_xor((int)w3, 32);
          const unsigned x0 = (unsigned)__shfl_xor((int)w0, 32);
          const unsigned x1 = (unsigned)__shfl_xor((int)w1, 32);
          union { unsigned u[4]; bf16x8 v; } pf;
          pf.u[0] = hi ? x2 : w0;
          pf.u[1] = hi ? x3 : w1;
          pf.u[2] = hi ? w2 : x0;
          pf.u[3] = hi ? w3 : x1;
          pfrag[jb] = pf.v;
        }
        __builtin_amdgcn_s_setprio(1);
#pragma unroll
        for (int dt = 0; dt < 2; ++dt) {
          const int row = dt * 32 + l31;
#pragma unroll
          for (int jb = 0; jb < 2; ++jb) {
            bf16x8 vt = *(const bf16x8*)(Vl + row * 128 + ((s * 64 + jb * 32 + hi * 16) ^ ((row & 7) << 4)));
            oacc[dt] = __builtin_amdgcn_mfma_f32_32x32x16_bf16(vt, pfrag[jb], oacc[dt], 0, 0, 0);
          }
        }
        __builtin_amdgcn_s_setprio(0);
      }
    }
    if (c < qb) WRITE((c + 1) & 1);
  }
  const float inv = 1.f / lsum;
  __hip_bfloat16* orow = o + (size_t)(b * T_SZ + q0w + l31) * E_SZ + h * HD_SZ;
#pragma unroll
  for (int dt = 0; dt < 2; ++dt) {
#pragma unroll
    for (int g = 0; g < 4; ++g) {
      union { __hip_bfloat16 hh[4]; short4 v; } ov;
#pragma unroll
      for (int e = 0; e < 4; ++e)
        ov.hh[e] = __float2bfloat16(oacc[dt][4 * g + e] * inv);
      *(short4*)(orow + dt * 32 + 4 * hi + 8 * g) = ov.v;
    }
  }
}

// ---------------------------------------------------------------------------
extern "C" void kernel_launch(void* const* d_in, const int* in_sizes, int n_in,
                              void* d_out, int out_size, void* d_ws, size_t ws_size,
                              hipStream_t stream) {
  const int* idx      = (const int*)d_in[0];
  const float* W_emb  = (const float*)d_in[1];
  const float* pos    = (const float*)d_in[2];
  const float* ln1_s  = (const float*)d_in[3];
  const float* ln1_b  = (const float*)d_in[4];
  const float* qkv_w  = (const float*)d_in[5];
  const float* proj_w = (const float*)d_in[6];
  const float* ln2_s  = (const float*)d_in[7];
  const float* ln2_b  = (const float*)d_in[8];
  const float* gate_w = (const float*)d_in[9];
  const float* up_w   = (const float*)d_in[10];
  const float* down_w = (const float*)d_in[11];
  const float* lnf_s  = (const float*)d_in[12];
  const float* lnf_b  = (const float*)d_in[13];
  float* out = (float*)d_out;

  char* p = (char*)d_ws;
  auto alloc = [&](size_t bytes) { char* q = p; p += (bytes + 255) & ~255ULL; return q; };
  float* x    = (float*)alloc((size_t)ROWS * E_SZ * 4);
  __hip_bfloat16* qkv_bf = (__hip_bfloat16*)alloc((size_t)ROWS * 3 * E_SZ * 2);
  __hip_bfloat16* h_bf  = (__hip_bfloat16*)alloc((size_t)ROWS * E_SZ * 2);
  __hip_bfloat16* o_bf  = (__hip_bfloat16*)alloc((size_t)ROWS * E_SZ * 2);
  __hip_bfloat16* g_bf  = (__hip_bfloat16*)alloc((size_t)ROWS * HID_PAD * 2);
  __hip_bfloat16* Wb    = (__hip_bfloat16*)alloc((size_t)V_PAD * E_SZ * 2);
  __hip_bfloat16* qkvwb = (__hip_bfloat16*)alloc((size_t)L_N * 3 * E_SZ * E_SZ * 2);
  __hip_bfloat16* projwb= (__hip_bfloat16*)alloc((size_t)L_N * E_SZ * E_SZ * 2);
  __hip_bfloat16* guwb  = (__hip_bfloat16*)alloc((size_t)L_N * 2816 * E_SZ * 2);
  __hip_bfloat16* downwb= (__hip_bfloat16*)alloc((size_t)L_N * E_SZ * HID_PAD * 2);

  // ---- weight prep: 5 batched launches ----
  convert_wemb<<<(V_PAD * E_SZ / 8 + 255) / 256, 256, 0, stream>>>(W_emb, Wb);
  transp_convert<<<dim3(3 * E_SZ / 32, E_SZ / 32, L_N), 256, 0, stream>>>(
      qkv_w, qkvwb, E_SZ, 3 * E_SZ, E_SZ, 3 * E_SZ);
  transp_convert<<<dim3(E_SZ / 32, E_SZ / 32, L_N), 256, 0, stream>>>(
      proj_w, projwb, E_SZ, E_SZ, E_SZ, E_SZ);
  gu_prep<<<dim3(HID_PAD / 32, E_SZ / 32, L_N), 256, 0, stream>>>(gate_w, up_w, guwb);
  transp_convert<<<dim3(E_SZ / 32, HID_PAD / 32, L_N), 256, 0, stream>>>(
      down_w, downwb, HID_SZ, E_SZ, HID_PAD, E_SZ);

  embed_kernel<<<ROWS, 128, 0, stream>>>(idx, W_emb, pos, x);

  for (int l = 0; l < L_N; ++l) {
    ln_kernel<<<ROWS, 256, 0, stream>>>(x, h_bf, ln1_s + l * E_SZ, ln1_b + l * E_SZ);
    mfma_gemm<1, false><<<dim3(12, 16), 256, 0, stream>>>(
        h_bf, qkvwb + (size_t)l * 3 * E_SZ * E_SZ, qkv_bf, nullptr, 3 * E_SZ, E_SZ);
    attn_mfma_kernel<<<B_SZ * H_N * (T_SZ / 64), 128, 0, stream>>>(qkv_bf, o_bf);
    mfma_gemm<2, false><<<dim3(4, 16), 256, 0, stream>>>(
        o_bf, projwb + (size_t)l * E_SZ * E_SZ, x, x, E_SZ, E_SZ);
    ln_kernel<<<ROWS, 256, 0, stream>>>(x, h_bf, ln2_s + l * E_SZ, ln2_b + l * E_SZ);
    mfma_gemm<3, false><<<dim3(22, 16), 256, 0, stream>>>(
        h_bf, guwb + (size_t)l * 2816 * E_SZ, g_bf, nullptr, 2816, E_SZ);
    mfma_gemm<2, false><<<dim3(4, 16), 256, 0, stream>>>(
        g_bf, downwb + (size_t)l * E_SZ * HID_PAD, x, x, E_SZ, HID_PAD);
  }

  ln_kernel<<<ROWS, 256, 0, stream>>>(x, h_bf, lnf_s, lnf_b);
  mfma_gemm<0, true><<<dim3(V_PAD / 128, 16), 256, 0, stream>>>(
      h_bf, Wb, out, nullptr, V_SZ, E_SZ);
}

// Round 7
// 1312.834 us; speedup vs baseline: 10.9518x; 1.0256x over previous
//
#include <hip/hip_runtime.h>
#include <hip/hip_bf16.h>
#include <math.h>

#define V_SZ 50257
#define V_PAD 50304
#define E_SZ 512
#define H_N 8
#define L_N 8
#define HID_SZ 1365
#define HID_PAD 1408
#define T_SZ 1024
#define B_SZ 2
#define HD_SZ 64
#define ROWS (B_SZ * T_SZ)   // 2048

typedef short bf16x8 __attribute__((ext_vector_type(8)));
typedef float f32x4 __attribute__((ext_vector_type(4)));
typedef float f32x16 __attribute__((ext_vector_type(16)));

// ---------------------------------------------------------------------------
// Embedding
// ---------------------------------------------------------------------------
__global__ __launch_bounds__(128) void embed_kernel(
    const int* __restrict__ idx, const float* __restrict__ W,
    const float* __restrict__ P, float* __restrict__ x) {
  const int bt = blockIdx.x;
  const int t = bt & (T_SZ - 1);
  const int id = idx[bt];
  const int e = threadIdx.x * 4;
  float4 w = *(const float4*)(W + (size_t)id * E_SZ + e);
  float4 p = *(const float4*)(P + (size_t)t * E_SZ + e);
  float4 r;
  r.x = w.x + p.x; r.y = w.y + p.y; r.z = w.z + p.z; r.w = w.w + p.w;
  *(float4*)(x + (size_t)bt * E_SZ + e) = r;
}

// ---------------------------------------------------------------------------
// LayerNorm f32 -> bf16
// ---------------------------------------------------------------------------
__global__ __launch_bounds__(256) void ln_kernel(
    const float* __restrict__ in, __hip_bfloat16* __restrict__ out,
    const float* __restrict__ sc, const float* __restrict__ bi) {
  const int row = blockIdx.x;
  const int tid = threadIdx.x;
  const float2 v = *(const float2*)(in + (size_t)row * E_SZ + tid * 2);
  float s = v.x + v.y;
#pragma unroll
  for (int o = 32; o; o >>= 1) s += __shfl_xor(s, o);
  __shared__ float w1[4], w2[4];
  if ((tid & 63) == 0) w1[tid >> 6] = s;
  __syncthreads();
  const float mean = (w1[0] + w1[1] + w1[2] + w1[3]) * (1.f / 512.f);
  const float d0 = v.x - mean, d1 = v.y - mean;
  float q = d0 * d0 + d1 * d1;
#pragma unroll
  for (int o = 32; o; o >>= 1) q += __shfl_xor(q, o);
  if ((tid & 63) == 0) w2[tid >> 6] = q;
  __syncthreads();
  const float var = (w2[0] + w2[1] + w2[2] + w2[3]) * (1.f / 512.f);
  const float inv = rsqrtf(var + 1e-5f);
  const float2 sv = *(const float2*)(sc + tid * 2);
  const float2 bv = *(const float2*)(bi + tid * 2);
  __hip_bfloat162 ov;
  ov.x = __float2bfloat16(d0 * inv * sv.x + bv.x);
  ov.y = __float2bfloat16(d1 * inv * sv.y + bv.y);
  *(__hip_bfloat162*)(out + (size_t)row * E_SZ + tid * 2) = ov;
}

// ---------------------------------------------------------------------------
// W_emb f32 -> bf16 (padded rows)
// ---------------------------------------------------------------------------
__global__ __launch_bounds__(256) void convert_wemb(
    const float* __restrict__ W, __hip_bfloat16* __restrict__ Wb) {
  const int tid = blockIdx.x * 256 + threadIdx.x;
  const int row = tid >> 6;
  const int c = (tid & 63) * 8;
  union { __hip_bfloat16 h[8]; int4 v; } u;
  if (row < V_SZ) {
    const float* p = W + (size_t)row * E_SZ + c;
#pragma unroll
    for (int j = 0; j < 8; ++j) u.h[j] = __float2bfloat16(p[j]);
  } else {
#pragma unroll
    for (int j = 0; j < 8; ++j) u.h[j] = __float2bfloat16(0.f);
  }
  *(int4*)(Wb + (size_t)row * E_SZ + c) = u.v;
}

// ---------------------------------------------------------------------------
// Batched transpose+convert [L][K][N] f32 -> [L][Npad][Kpad] bf16
// ---------------------------------------------------------------------------
__global__ __launch_bounds__(256) void transp_convert(
    const float* __restrict__ in, __hip_bfloat16* __restrict__ out,
    int K, int N, int Kpad, int Npad) {
  __shared__ float tile[32][33];
  const int l = blockIdx.z;
  in  += (size_t)l * K * N;
  out += (size_t)l * Npad * Kpad;
  const int tx = threadIdx.x & 31, ty = threadIdx.x >> 5;
  const int n0 = blockIdx.x * 32, k0 = blockIdx.y * 32;
#pragma unroll
  for (int i = 0; i < 4; ++i) {
    const int k = k0 + ty + i * 8, n = n0 + tx;
    tile[ty + i * 8][tx] = (k < K && n < N) ? in[(size_t)k * N + n] : 0.f;
  }
  __syncthreads();
#pragma unroll
  for (int i = 0; i < 4; ++i) {
    const int n = n0 + ty + i * 8, kk = k0 + tx;
    out[(size_t)n * Kpad + kk] = __float2bfloat16(tile[tx][ty + i * 8]);
  }
}

// ---------------------------------------------------------------------------
// gate/up interleaved prep (coalesced)
// ---------------------------------------------------------------------------
__global__ __launch_bounds__(256) void gu_prep(
    const float* __restrict__ gate, const float* __restrict__ up,
    __hip_bfloat16* __restrict__ outw) {
  __shared__ float tile[32][33];
  const int l = blockIdx.z;
  const int c0 = blockIdx.x * 32, k0 = blockIdx.y * 32;
  const int tx = threadIdx.x & 31, ty = threadIdx.x >> 5;
#pragma unroll
  for (int role = 0; role < 2; ++role) {
    const float* src = (role ? up : gate) + (size_t)l * E_SZ * HID_SZ;
#pragma unroll
    for (int i = 0; i < 4; ++i) {
      const int k = k0 + ty + i * 8, c = c0 + tx;
      tile[ty + i * 8][tx] = (c < HID_SZ) ? src[(size_t)k * HID_SZ + c] : 0.f;
    }
    __syncthreads();
#pragma unroll
    for (int i = 0; i < 4; ++i) {
      const int c = c0 + ty + i * 8, kk = k0 + tx;
      const int n = ((c >> 4) << 5) | (role << 4) | (c & 15);
      outw[((size_t)l * 2816 + n) * E_SZ + kk] = __float2bfloat16(tile[tx][ty + i * 8]);
    }
    __syncthreads();
  }
}

// ---------------------------------------------------------------------------
// bf16 MFMA GEMM 128x128 (m97 structure) + T2 swizzle (src-preswizzle + read XOR)
// EPI: 0 f32, 1 bf16, 2 f32+residual, 3 SwiGLU->bf16
// ---------------------------------------------------------------------------
template <int EPI, bool BOUND>
__global__ __launch_bounds__(256) void mfma_gemm(
    const __hip_bfloat16* __restrict__ A, const __hip_bfloat16* __restrict__ B,
    void* __restrict__ Cv, const float* __restrict__ R, int N, int K) {
  __shared__ char lds[16384];
  const int tid = threadIdx.x;
  const int lane = tid & 63, w = tid >> 6;
  const int wr = w >> 1, wc = w & 1;
  const int m0 = blockIdx.y * 128, n0 = blockIdx.x * 128;
  const size_t SA = (size_t)K * 2;

  f32x4 acc[4][4] = {};
  char* As = lds;
  char* Bs = lds + 8192;
  const char* Ab = (const char*)A + (size_t)m0 * SA;
  const char* Bb = (const char*)B + (size_t)n0 * SA;

  const int r = lane >> 2;
  const int cb2 = ((lane & 3) * 16) ^ (((lane >> 2) & 3) << 4);  // swizzled src chunk
  const int kbx = ((lane >> 4) * 16) ^ ((lane & 3) << 4);        // swizzled read byte
  for (int k0 = 0; k0 < K; k0 += 32) {
#pragma unroll
    for (int cc2 = 0; cc2 < 2; ++cc2) {
      const int c = w * 2 + cc2;
      const char* ga = Ab + (size_t)(c * 16 + r) * SA + k0 * 2 + cb2;
      __builtin_amdgcn_global_load_lds(
          (const __attribute__((address_space(1))) unsigned int*)ga,
          (__attribute__((address_space(3))) unsigned int*)(As + c * 1024),
          16, 0, 0);
      const char* gb = Bb + (size_t)(c * 16 + r) * SA + k0 * 2 + cb2;
      __builtin_amdgcn_global_load_lds(
          (const __attribute__((address_space(1))) unsigned int*)gb,
          (__attribute__((address_space(3))) unsigned int*)(Bs + c * 1024),
          16, 0, 0);
    }
    __syncthreads();
    bf16x8 a[4], b[4];
#pragma unroll
    for (int i = 0; i < 4; ++i) {
      a[i] = *(const bf16x8*)(As + (wr * 64 + i * 16 + (lane & 15)) * 64 + kbx);
      b[i] = *(const bf16x8*)(Bs + (wc * 64 + i * 16 + (lane & 15)) * 64 + kbx);
    }
#pragma unroll
    for (int i = 0; i < 4; ++i)
#pragma unroll
      for (int j = 0; j < 4; ++j)
        acc[i][j] = __builtin_amdgcn_mfma_f32_16x16x32_bf16(a[i], b[j], acc[i][j], 0, 0, 0);
    __syncthreads();
  }

  const int cr = (lane >> 4) * 4, ccol = lane & 15;
  if (EPI == 3) {
    __hip_bfloat16* G = (__hip_bfloat16*)Cv;
#pragma unroll
    for (int i = 0; i < 4; ++i) {
#pragma unroll
      for (int p = 0; p < 2; ++p) {
        const int cg = (n0 >> 1) + wc * 32 + p * 16 + ccol;
#pragma unroll
        for (int rr = 0; rr < 4; ++rr) {
          const int m = m0 + wr * 64 + i * 16 + cr + rr;
          const float gv = acc[i][2 * p][rr];
          const float uv = acc[i][2 * p + 1][rr];
          const float val = gv / (1.f + __expf(-gv)) * uv;
          G[(size_t)m * HID_PAD + cg] = __float2bfloat16(val);
        }
      }
    }
    return;
  }
#pragma unroll
  for (int i = 0; i < 4; ++i) {
#pragma unroll
    for (int j = 0; j < 4; ++j) {
      const int n = n0 + wc * 64 + j * 16 + ccol;
      if (BOUND && n >= N) continue;
#pragma unroll
      for (int rr = 0; rr < 4; ++rr) {
        const int m = m0 + wr * 64 + i * 16 + cr + rr;
        float v = acc[i][j][rr];
        if (EPI == 2) v += R[(size_t)m * N + n];
        if (EPI == 1) ((__hip_bfloat16*)Cv)[(size_t)m * N + n] = __float2bfloat16(v);
        else ((float*)Cv)[(size_t)m * N + n] = v;
      }
    }
  }
}

// ---------------------------------------------------------------------------
// 64x64-tile GEMM (BK=64, 4 waves, swizzled) for small-N GEMMs (proj/down).
// C(f32) = A@B^T + R. Grid (N/64, M/64).
// ---------------------------------------------------------------------------
__global__ __launch_bounds__(256) void gemm64(
    const __hip_bfloat16* __restrict__ A, const __hip_bfloat16* __restrict__ B,
    float* __restrict__ C, const float* __restrict__ R, int N, int K) {
  __shared__ char lds[16384];
  const int tid = threadIdx.x, lane = tid & 63, w = tid >> 6;
  const int wr = w >> 1, wc = w & 1;
  const int m0 = blockIdx.y * 64, n0 = blockIdx.x * 64;
  const size_t SA = (size_t)K * 2;
  char* As = lds;
  char* Bs = lds + 8192;
  const char* Ab = (const char*)A + (size_t)m0 * SA;
  const char* Bb = (const char*)B + (size_t)n0 * SA;
  f32x4 acc[2][2] = {};
  const int lrow = lane >> 3;               // 0..7
  const int schunk = ((lane & 7) ^ lrow) * 16;  // swizzled source chunk byte
  const int kb = (lane >> 4) * 16;

  for (int k0 = 0; k0 < K; k0 += 64) {
#pragma unroll
    for (int i = 0; i < 2; ++i) {
      const int row = w * 8 + 32 * i + lrow;
      const char* ga = Ab + (size_t)row * SA + k0 * 2 + schunk;
      __builtin_amdgcn_global_load_lds(
          (const __attribute__((address_space(1))) unsigned int*)ga,
          (__attribute__((address_space(3))) unsigned int*)(As + w * 1024 + i * 4096),
          16, 0, 0);
      const char* gb = Bb + (size_t)row * SA + k0 * 2 + schunk;
      __builtin_amdgcn_global_load_lds(
          (const __attribute__((address_space(1))) unsigned int*)gb,
          (__attribute__((address_space(3))) unsigned int*)(Bs + w * 1024 + i * 4096),
          16, 0, 0);
    }
    __syncthreads();
    bf16x8 a[2][2], bb[2][2];
#pragma unroll
    for (int i = 0; i < 2; ++i) {
      const int ra = wr * 32 + i * 16 + (lane & 15);
      const int rb = wc * 32 + i * 16 + (lane & 15);
#pragma unroll
      for (int ks = 0; ks < 2; ++ks) {
        a[i][ks]  = *(const bf16x8*)(As + ra * 128 + ((ks * 64 + kb) ^ ((ra & 7) << 4)));
        bb[i][ks] = *(const bf16x8*)(Bs + rb * 128 + ((ks * 64 + kb) ^ ((rb & 7) << 4)));
      }
    }
#pragma unroll
    for (int ks = 0; ks < 2; ++ks)
#pragma unroll
      for (int i = 0; i < 2; ++i)
#pragma unroll
        for (int j = 0; j < 2; ++j)
          acc[i][j] = __builtin_amdgcn_mfma_f32_16x16x32_bf16(a[i][ks], bb[j][ks], acc[i][j], 0, 0, 0);
    __syncthreads();
  }

  const int cr = (lane >> 4) * 4, ccol = lane & 15;
#pragma unroll
  for (int i = 0; i < 2; ++i)
#pragma unroll
    for (int j = 0; j < 2; ++j) {
      const int n = n0 + wc * 32 + j * 16 + ccol;
#pragma unroll
      for (int rr = 0; rr < 4; ++rr) {
        const int m = m0 + wr * 32 + i * 16 + cr + rr;
        C[(size_t)m * N + n] = acc[i][j][rr] + R[(size_t)m * N + n];
      }
    }
}

// ---------------------------------------------------------------------------
// Flash attention, 32x32x16 MFMA, swapped operands, KVBLK=128, double-buffered
// staging, TWO independent softmax streams (even/odd 32-kv sub-blocks) merged
// at the end, defer-max (THR=8).
// ---------------------------------------------------------------------------
__global__ __launch_bounds__(128, 1) void attn_mfma_kernel(
    const __hip_bfloat16* __restrict__ qkv, __hip_bfloat16* __restrict__ o) {
  const int bid = blockIdx.x;
  const int qb = bid & 15;
  const int h = (bid >> 4) & 7;
  const int b = bid >> 7;
  const int tid = threadIdx.x;
  const int w = tid >> 6, lane = tid & 63;
  const int l31 = lane & 31, hi = lane >> 5;
  const int q0w = qb * 64 + 32 * w;
  const float slope = exp2f(-(float)(h + 1));
  const int rowstride = 3 * E_SZ;
  const int nch = (qb + 2) >> 1;

  __shared__ char lds[65536];   // 2 buf x (K 16KB + VT 16KB)

  bf16x8 qf[4];
  {
    const __hip_bfloat16* qrow = qkv + (size_t)(b * T_SZ + q0w + l31) * rowstride + h * HD_SZ;
#pragma unroll
    for (int dblk = 0; dblk < 4; ++dblk)
      qf[dblk] = *(const bf16x8*)(qrow + dblk * 16 + hi * 8);
  }

  f32x16 oacc[2][2] = {};
  float m[2] = {-INFINITY, -INFINITY}, lsum[2] = {0.f, 0.f};

  // staging geometry: K -> one full row (64d=128B) per thread;
  // V -> 4 j-rows x 16 d per thread, written transposed.
  int4 kreg[8];
  int4 vr[4][2];
  const int jK = tid;                       // 0..127
  const int jqV = tid >> 2, qtV = tid & 3;  // j0 = jqV*4, d0 = qtV*16
  const int d0V = qtV * 16;

  auto ISSUE = [&](int c) {
    const __hip_bfloat16* srcK = qkv + (size_t)(b * T_SZ + c * 128 + jK) * rowstride + E_SZ + h * HD_SZ;
#pragma unroll
    for (int ch = 0; ch < 8; ++ch) kreg[ch] = ((const int4*)srcK)[ch];
    const __hip_bfloat16* srcV = qkv + (size_t)(b * T_SZ + c * 128 + jqV * 4) * rowstride + 2 * E_SZ + h * HD_SZ + d0V;
#pragma unroll
    for (int rr = 0; rr < 4; ++rr) {
      vr[rr][0] = ((const int4*)(srcV + rr * rowstride))[0];
      vr[rr][1] = ((const int4*)(srcV + rr * rowstride))[1];
    }
  };
  auto WRITE = [&](int bufidx) {
    char* Kb = lds + bufidx * 32768;
    char* Vb = Kb + 16384;
#pragma unroll
    for (int ch = 0; ch < 8; ++ch)
      *(int4*)(Kb + jK * 128 + ((ch * 16) ^ ((jK & 7) << 4))) = kreg[ch];
    union { int4 v[2]; unsigned short us[16]; } r0, r1, r2, r3;
    r0.v[0] = vr[0][0]; r0.v[1] = vr[0][1];
    r1.v[0] = vr[1][0]; r1.v[1] = vr[1][1];
    r2.v[0] = vr[2][0]; r2.v[1] = vr[2][1];
    r3.v[0] = vr[3][0]; r3.v[1] = vr[3][1];
#pragma unroll
    for (int e = 0; e < 16; ++e) {
      const int d = d0V + e;
      uint2 wv;
      wv.x = (unsigned)r0.us[e] | ((unsigned)r1.us[e] << 16);
      wv.y = (unsigned)r2.us[e] | ((unsigned)r3.us[e] << 16);
      *(uint2*)(Vb + d * 256 + ((jqV * 8) ^ ((d & 7) << 4))) = wv;
    }
  };

  ISSUE(0);
  WRITE(0);
  for (int c = 0; c < nch; ++c) {
    if (c + 1 < nch) ISSUE(c + 1);
    __syncthreads();
    const char* Kl = lds + (c & 1) * 32768;
    const char* Vl = Kl + 16384;
#pragma unroll
    for (int s = 0; s < 4; ++s) {
      const int j0 = c * 128 + 32 * s;
      if (j0 <= q0w + 31) {
        const int st = s & 1;
        f32x16 sacc = {};
        const int jrow = 32 * s + l31;
        __builtin_amdgcn_s_setprio(1);
#pragma unroll
        for (int dblk = 0; dblk < 4; ++dblk) {
          bf16x8 kf = *(const bf16x8*)(Kl + jrow * 128 + ((dblk * 32 + hi * 16) ^ ((jrow & 7) << 4)));
          sacc = __builtin_amdgcn_mfma_f32_32x32x16_bf16(kf, qf[dblk], sacc, 0, 0, 0);
        }
        __builtin_amdgcn_s_setprio(0);
        const int qg = q0w + l31;
        float p[16];
        float tmax = -1e30f;
#pragma unroll
        for (int r = 0; r < 16; ++r) {
          const int jg = j0 + (r & 3) + 8 * (r >> 2) + 4 * hi;
          const float sv = (jg > qg) ? -1e9f : (sacc[r] * 0.125f + slope * (float)(qg - jg));
          p[r] = sv;
          tmax = fmaxf(tmax, sv);
        }
        tmax = fmaxf(tmax, __shfl_xor(tmax, 32));
        // defer-max: skip rescale when tile max doesn't exceed running max + 8
        if (!__all(tmax <= m[st] + 8.f)) {
          const float mnew = fmaxf(m[st], tmax);
          const float corr = __expf(m[st] - mnew);
          lsum[st] *= corr;
#pragma unroll
          for (int dt = 0; dt < 2; ++dt)
#pragma unroll
            for (int r = 0; r < 16; ++r) oacc[st][dt][r] *= corr;
          m[st] = mnew;
        }
        float tsum = 0.f;
#pragma unroll
        for (int r = 0; r < 16; ++r) {
          p[r] = __expf(p[r] - m[st]);
          tsum += p[r];
        }
        tsum += __shfl_xor(tsum, 32);
        lsum[st] += tsum;
        unsigned wds[8];
#pragma unroll
        for (int k = 0; k < 8; ++k) {
          union { __hip_bfloat16 hh[2]; unsigned u; } pk_;
          pk_.hh[0] = __float2bfloat16(p[2 * k]);
          pk_.hh[1] = __float2bfloat16(p[2 * k + 1]);
          wds[k] = pk_.u;
        }
        bf16x8 pfrag[2];
#pragma unroll
        for (int jb = 0; jb < 2; ++jb) {
          const unsigned w0 = wds[4 * jb + 0], w1 = wds[4 * jb + 1];
          const unsigned w2 = wds[4 * jb + 2], w3 = wds[4 * jb + 3];
          const unsigned x2 = (unsigned)__shfl_xor((int)w2, 32);
          const unsigned x3 = (unsigned)__shfl_xor((int)w3, 32);
          const unsigned x0 = (unsigned)__shfl_xor((int)w0, 32);
          const unsigned x1 = (unsigned)__shfl_xor((int)w1, 32);
          union { unsigned u[4]; bf16x8 v; } pf;
          pf.u[0] = hi ? x2 : w0;
          pf.u[1] = hi ? x3 : w1;
          pf.u[2] = hi ? w2 : x0;
          pf.u[3] = hi ? w3 : x1;
          pfrag[jb] = pf.v;
        }
        __builtin_amdgcn_s_setprio(1);
#pragma unroll
        for (int dt = 0; dt < 2; ++dt) {
          const int row = dt * 32 + l31;
#pragma unroll
          for (int jb = 0; jb < 2; ++jb) {
            bf16x8 vt = *(const bf16x8*)(Vl + row * 256 + ((s * 64 + jb * 32 + hi * 16) ^ ((row & 7) << 4)));
            oacc[st][dt] = __builtin_amdgcn_mfma_f32_32x32x16_bf16(vt, pfrag[jb], oacc[st][dt], 0, 0, 0);
          }
        }
        __builtin_amdgcn_s_setprio(0);
      }
    }
    if (c + 1 < nch) WRITE((c + 1) & 1);
  }

  // merge streams
  const float mm = fmaxf(m[0], m[1]);
  const float wA = __expf(m[0] - mm), wB = __expf(m[1] - mm);
  const float inv = 1.f / (lsum[0] * wA + lsum[1] * wB);
  __hip_bfloat16* orow = o + (size_t)(b * T_SZ + q0w + l31) * E_SZ + h * HD_SZ;
#pragma unroll
  for (int dt = 0; dt < 2; ++dt) {
#pragma unroll
    for (int g = 0; g < 4; ++g) {
      union { __hip_bfloat16 hh[4]; short4 v; } ov;
#pragma unroll
      for (int e = 0; e < 4; ++e)
        ov.hh[e] = __float2bfloat16((oacc[0][dt][4 * g + e] * wA + oacc[1][dt][4 * g + e] * wB) * inv);
      *(short4*)(orow + dt * 32 + 4 * hi + 8 * g) = ov.v;
    }
  }
}

// ---------------------------------------------------------------------------
extern "C" void kernel_launch(void* const* d_in, const int* in_sizes, int n_in,
                              void* d_out, int out_size, void* d_ws, size_t ws_size,
                              hipStream_t stream) {
  const int* idx      = (const int*)d_in[0];
  const float* W_emb  = (const float*)d_in[1];
  const float* pos    = (const float*)d_in[2];
  const float* ln1_s  = (const float*)d_in[3];
  const float* ln1_b  = (const float*)d_in[4];
  const float* qkv_w  = (const float*)d_in[5];
  const float* proj_w = (const float*)d_in[6];
  const float* ln2_s  = (const float*)d_in[7];
  const float* ln2_b  = (const float*)d_in[8];
  const float* gate_w = (const float*)d_in[9];
  const float* up_w   = (const float*)d_in[10];
  const float* down_w = (const float*)d_in[11];
  const float* lnf_s  = (const float*)d_in[12];
  const float* lnf_b  = (const float*)d_in[13];
  float* out = (float*)d_out;

  char* p = (char*)d_ws;
  auto alloc = [&](size_t bytes) { char* q = p; p += (bytes + 255) & ~255ULL; return q; };
  float* x    = (float*)alloc((size_t)ROWS * E_SZ * 4);
  __hip_bfloat16* qkv_bf = (__hip_bfloat16*)alloc((size_t)ROWS * 3 * E_SZ * 2);
  __hip_bfloat16* h_bf  = (__hip_bfloat16*)alloc((size_t)ROWS * E_SZ * 2);
  __hip_bfloat16* o_bf  = (__hip_bfloat16*)alloc((size_t)ROWS * E_SZ * 2);
  __hip_bfloat16* g_bf  = (__hip_bfloat16*)alloc((size_t)ROWS * HID_PAD * 2);
  __hip_bfloat16* Wb    = (__hip_bfloat16*)alloc((size_t)V_PAD * E_SZ * 2);
  __hip_bfloat16* qkvwb = (__hip_bfloat16*)alloc((size_t)L_N * 3 * E_SZ * E_SZ * 2);
  __hip_bfloat16* projwb= (__hip_bfloat16*)alloc((size_t)L_N * E_SZ * E_SZ * 2);
  __hip_bfloat16* guwb  = (__hip_bfloat16*)alloc((size_t)L_N * 2816 * E_SZ * 2);
  __hip_bfloat16* downwb= (__hip_bfloat16*)alloc((size_t)L_N * E_SZ * HID_PAD * 2);

  // ---- weight prep ----
  convert_wemb<<<(V_PAD * E_SZ / 8 + 255) / 256, 256, 0, stream>>>(W_emb, Wb);
  transp_convert<<<dim3(3 * E_SZ / 32, E_SZ / 32, L_N), 256, 0, stream>>>(
      qkv_w, qkvwb, E_SZ, 3 * E_SZ, E_SZ, 3 * E_SZ);
  transp_convert<<<dim3(E_SZ / 32, E_SZ / 32, L_N), 256, 0, stream>>>(
      proj_w, projwb, E_SZ, E_SZ, E_SZ, E_SZ);
  gu_prep<<<dim3(HID_PAD / 32, E_SZ / 32, L_N), 256, 0, stream>>>(gate_w, up_w, guwb);
  transp_convert<<<dim3(E_SZ / 32, HID_PAD / 32, L_N), 256, 0, stream>>>(
      down_w, downwb, HID_SZ, E_SZ, HID_PAD, E_SZ);

  embed_kernel<<<ROWS, 128, 0, stream>>>(idx, W_emb, pos, x);

  for (int l = 0; l < L_N; ++l) {
    ln_kernel<<<ROWS, 256, 0, stream>>>(x, h_bf, ln1_s + l * E_SZ, ln1_b + l * E_SZ);
    mfma_gemm<1, false><<<dim3(12, 16), 256, 0, stream>>>(
        h_bf, qkvwb + (size_t)l * 3 * E_SZ * E_SZ, qkv_bf, nullptr, 3 * E_SZ, E_SZ);
    attn_mfma_kernel<<<B_SZ * H_N * (T_SZ / 64), 128, 0, stream>>>(qkv_bf, o_bf);
    gemm64<<<dim3(E_SZ / 64, ROWS / 64), 256, 0, stream>>>(
        o_bf, projwb + (size_t)l * E_SZ * E_SZ, x, x, E_SZ, E_SZ);
    ln_kernel<<<ROWS, 256, 0, stream>>>(x, h_bf, ln2_s + l * E_SZ, ln2_b + l * E_SZ);
    mfma_gemm<3, false><<<dim3(22, 16), 256, 0, stream>>>(
        h_bf, guwb + (size_t)l * 2816 * E_SZ, g_bf, nullptr, 2816, E_SZ);
    gemm64<<<dim3(E_SZ / 64, ROWS / 64), 256, 0, stream>>>(
        g_bf, downwb + (size_t)l * E_SZ * HID_PAD, x, x, E_SZ, HID_PAD);
  }

  ln_kernel<<<ROWS, 256, 0, stream>>>(x, h_bf, lnf_s, lnf_b);
  mfma_gemm<0, true><<<dim3(V_PAD / 128, 16), 256, 0, stream>>>(
      h_bf, Wb, out, nullptr, V_SZ, E_SZ);
}